// Round 1
// baseline (483.972 us; speedup 1.0000x reference)
//
#include <hip/hip_runtime.h>
#include <hip/hip_bf16.h>

// Qwen3VL vision attention, MI355X. Round 1: correctness-first MFMA pipeline.
// S=4096 E=1152 H=16 D=72 (padded to 96), 4 chunks of 1024.
// Precision plan: split-bf16 (hi+lo) QKV GEMM -> near-fp32 q,k,v; plain bf16
// MFMA for QK^T / PV / proj; softmax in fp32. Threshold 5.35e-3.

#define S_TOT 4096
#define E_DIM 1152
#define NH    16
#define HD    72
#define HDP   96      // D padded to 96 for uniform K-steps of 32
#define CLEN  1024

static constexpr float SCALE_QK = 0.11785113019775793f;  // 72^-0.5

typedef __bf16 bf16x8 __attribute__((ext_vector_type(8)));
typedef float  f32x4  __attribute__((ext_vector_type(4)));
typedef __hip_bfloat16 bf16;

// ---- async global->LDS, 16B per lane; LDS dest must be wave-uniform ----
__device__ __forceinline__ void gld_lds16(const void* g, void* l) {
  __builtin_amdgcn_global_load_lds(
      (const __attribute__((address_space(1))) unsigned int*)g,
      (__attribute__((address_space(3))) unsigned int*)l, 16, 0, 0);
}

// Stage a 128x32 bf16 tile (row-major, row stride ld elements) into LDS.
// 8 wave-calls of 1024B: call = w*2+c; lane covers 8 bf16 along K.
__device__ __forceinline__ void stage128x32(const bf16* src, int ld, bf16* dst,
                                            int w, int ln) {
#pragma unroll
  for (int c = 0; c < 2; ++c) {
    const int f = ((w * 2 + c) * 64 + ln) * 8;       // flat bf16 idx in tile
    gld_lds16(src + (f >> 5) * ld + (f & 31), dst + (w * 2 + c) * 512);
  }
}

// ---------------- pack fp32 -> bf16 (hi) and residual (lo) ----------------
__global__ void k_pack_split(const float* __restrict__ x, bf16* __restrict__ hi,
                             bf16* __restrict__ lo) {
  const int i = blockIdx.x * blockDim.x + threadIdx.x;
  const float4 v = ((const float4*)x)[i];
  const float f0 = v.x, f1 = v.y, f2 = v.z, f3 = v.w;
  bf16 h0 = __float2bfloat16(f0), h1 = __float2bfloat16(f1);
  bf16 h2 = __float2bfloat16(f2), h3 = __float2bfloat16(f3);
  hi[4 * i + 0] = h0; hi[4 * i + 1] = h1; hi[4 * i + 2] = h2; hi[4 * i + 3] = h3;
  lo[4 * i + 0] = __float2bfloat16(f0 - __bfloat162float(h0));
  lo[4 * i + 1] = __float2bfloat16(f1 - __bfloat162float(h1));
  lo[4 * i + 2] = __float2bfloat16(f2 - __bfloat162float(h2));
  lo[4 * i + 3] = __float2bfloat16(f3 - __bfloat162float(h3));
}

__global__ void k_pack_plain(const float* __restrict__ x, bf16* __restrict__ y) {
  const int i = blockIdx.x * blockDim.x + threadIdx.x;
  const float4 v = ((const float4*)x)[i];
  y[4 * i + 0] = __float2bfloat16(v.x);
  y[4 * i + 1] = __float2bfloat16(v.y);
  y[4 * i + 2] = __float2bfloat16(v.z);
  y[4 * i + 3] = __float2bfloat16(v.w);
}

// ---------------- QKV GEMM, split-bf16 (3 MFMAs per fragment) -------------
// C[4096,3456] = hs @ qkv_w^T + b. Writes q,k sections fp32; v section bf16.
__global__ __launch_bounds__(256, 2)
void k_qkv_gemm(const bf16* __restrict__ Ahi, const bf16* __restrict__ Alo,
                const bf16* __restrict__ Whi, const bf16* __restrict__ Wlo,
                const float* __restrict__ bias, float* __restrict__ Eq,
                float* __restrict__ Ek, bf16* __restrict__ Vb) {
  __shared__ bf16 sAh[128 * 32], sAl[128 * 32], sBh[128 * 32], sBl[128 * 32];
  const int w = threadIdx.x >> 6, ln = threadIdx.x & 63;
  const int m0 = blockIdx.x * 128, n0 = blockIdx.y * 128;
  const bf16* Ah = Ahi + (size_t)m0 * E_DIM;
  const bf16* Al = Alo + (size_t)m0 * E_DIM;
  const bf16* Bh = Whi + (size_t)n0 * E_DIM;
  const bf16* Bl = Wlo + (size_t)n0 * E_DIM;
  const int r = ln & 15, g = ln >> 4;
  const int wr = (w >> 1) * 64, wc = (w & 1) * 64;
  f32x4 acc[4][4] = {};
  for (int k0 = 0; k0 < E_DIM; k0 += 32) {
    __syncthreads();
    stage128x32(Ah + k0, E_DIM, sAh, w, ln);
    stage128x32(Al + k0, E_DIM, sAl, w, ln);
    stage128x32(Bh + k0, E_DIM, sBh, w, ln);
    stage128x32(Bl + k0, E_DIM, sBl, w, ln);
    __syncthreads();
    bf16x8 ah[4], al[4];
#pragma unroll
    for (int m = 0; m < 4; ++m) {
      ah[m] = *(const bf16x8*)&sAh[(wr + m * 16 + r) * 32 + g * 8];
      al[m] = *(const bf16x8*)&sAl[(wr + m * 16 + r) * 32 + g * 8];
    }
#pragma unroll
    for (int n = 0; n < 4; ++n) {
      bf16x8 bh = *(const bf16x8*)&sBh[(wc + n * 16 + r) * 32 + g * 8];
      bf16x8 bl = *(const bf16x8*)&sBl[(wc + n * 16 + r) * 32 + g * 8];
#pragma unroll
      for (int m = 0; m < 4; ++m) {
        acc[m][n] = __builtin_amdgcn_mfma_f32_16x16x32_bf16(ah[m], bh, acc[m][n], 0, 0, 0);
        acc[m][n] = __builtin_amdgcn_mfma_f32_16x16x32_bf16(al[m], bh, acc[m][n], 0, 0, 0);
        acc[m][n] = __builtin_amdgcn_mfma_f32_16x16x32_bf16(ah[m], bl, acc[m][n], 0, 0, 0);
      }
    }
  }
  // C/D layout: col = lane&15, row = (lane>>4)*4 + j  [HW-verified mapping]
  const int sect = n0 / E_DIM;  // 128-col tile lies fully in one of q/k/v
#pragma unroll
  for (int n = 0; n < 4; ++n) {
    const int col = n0 + wc + n * 16 + r;
    const float bv = bias[col];
    const int cl = col - sect * E_DIM;
#pragma unroll
    for (int m = 0; m < 4; ++m)
#pragma unroll
      for (int j = 0; j < 4; ++j) {
        const int row = m0 + wr + m * 16 + g * 4 + j;
        const float v = acc[m][n][j] + bv;
        if (sect == 0)      Eq[(size_t)row * E_DIM + cl] = v;
        else if (sect == 1) Ek[(size_t)row * E_DIM + cl] = v;
        else                Vb[(size_t)row * E_DIM + cl] = __float2bfloat16(v);
      }
  }
}

// ---------------- V transpose: Vb[s][h*72+d] -> Vt[h][d(96)][s] -----------
__global__ void k_vtrans(const bf16* __restrict__ Vb, bf16* __restrict__ Vt) {
  __shared__ bf16 t[32][33];
  const int hd0 = blockIdx.x * 32, s0 = blockIdx.y * 32;
  const int tx = threadIdx.x, ty = threadIdx.y;  // 32 x 8
#pragma unroll
  for (int k = 0; k < 4; ++k)
    t[ty + 8 * k][tx] = Vb[(size_t)(s0 + ty + 8 * k) * E_DIM + hd0 + tx];
  __syncthreads();
#pragma unroll
  for (int k = 0; k < 4; ++k) {
    const int hd = hd0 + ty + 8 * k;
    const int hh = hd / HD, dd = hd % HD;
    Vt[((size_t)hh * HDP + dd) * S_TOT + s0 + tx] = t[tx][ty + 8 * k];
  }
}

// ---------------- RoPE (fp32) -> bf16 q,k with D padded to 96 -------------
__global__ void k_rope(const float* __restrict__ Eq, const float* __restrict__ Ek,
                       const float* __restrict__ cs, const float* __restrict__ sn,
                       bf16* __restrict__ Qb, bf16* __restrict__ Kb) {
  const int i = blockIdx.x * 256 + threadIdx.x;  // over 4096*16*36
  const int d = i % 36;
  const int h = (i / 36) & 15;
  const int s = i / (36 * 16);
  if (s >= S_TOT) return;
  const float c0 = cs[s * HD + d], s0 = sn[s * HD + d];
  const float c1 = cs[s * HD + d + 36], s1 = sn[s * HD + d + 36];
  const size_t qi = (size_t)s * E_DIM + h * HD;
  const size_t qo = (size_t)s * (NH * HDP) + h * HDP;
  {
    const float x0 = Eq[qi + d], x1 = Eq[qi + d + 36];
    Qb[qo + d]      = __float2bfloat16(x0 * c0 - x1 * s0);
    Qb[qo + d + 36] = __float2bfloat16(x1 * c1 + x0 * s1);
  }
  {
    const float x0 = Ek[qi + d], x1 = Ek[qi + d + 36];
    Kb[qo + d]      = __float2bfloat16(x0 * c0 - x1 * s0);
    Kb[qo + d + 36] = __float2bfloat16(x1 * c1 + x0 * s1);
  }
}

// ---------------- scores = scale * Q K^T per (chunk,head) -----------------
__global__ __launch_bounds__(256, 2)
void k_qk(const bf16* __restrict__ Qb, const bf16* __restrict__ Kb,
          float* __restrict__ Sc, int s0) {
  __shared__ bf16 sA[128 * 32], sB[128 * 32];
  const int w = threadIdx.x >> 6, ln = threadIdx.x & 63;
  const int h = blockIdx.z;
  const int m0 = blockIdx.x * 128, n0 = blockIdx.y * 128;
  const bf16* A = Qb + (size_t)(s0 + m0) * (NH * HDP) + h * HDP;
  const bf16* B = Kb + (size_t)(s0 + n0) * (NH * HDP) + h * HDP;
  const int r = ln & 15, g = ln >> 4;
  const int wr = (w >> 1) * 64, wc = (w & 1) * 64;
  f32x4 acc[4][4] = {};
  for (int k0 = 0; k0 < HDP; k0 += 32) {
    __syncthreads();
    stage128x32(A + k0, NH * HDP, sA, w, ln);
    stage128x32(B + k0, NH * HDP, sB, w, ln);
    __syncthreads();
    bf16x8 a[4];
#pragma unroll
    for (int m = 0; m < 4; ++m)
      a[m] = *(const bf16x8*)&sA[(wr + m * 16 + r) * 32 + g * 8];
#pragma unroll
    for (int n = 0; n < 4; ++n) {
      bf16x8 bv = *(const bf16x8*)&sB[(wc + n * 16 + r) * 32 + g * 8];
#pragma unroll
      for (int m = 0; m < 4; ++m)
        acc[m][n] = __builtin_amdgcn_mfma_f32_16x16x32_bf16(a[m], bv, acc[m][n], 0, 0, 0);
    }
  }
  float* C = Sc + ((size_t)h * CLEN + m0) * CLEN + n0;
#pragma unroll
  for (int n = 0; n < 4; ++n)
#pragma unroll
    for (int m = 0; m < 4; ++m)
#pragma unroll
      for (int j = 0; j < 4; ++j)
        C[(size_t)(wr + m * 16 + g * 4 + j) * CLEN + wc + n * 16 + r] =
            acc[m][n][j] * SCALE_QK;
}

// ------- softmax over each row of 1024 fp32; writes probs bf16 in place ---
// probs row i lives at byte offset i*4096 (row stride 2048 bf16 elements).
__global__ __launch_bounds__(256)
void k_softmax(float* __restrict__ Sc) {
  float* rp = Sc + (size_t)blockIdx.x * CLEN;
  const int t = threadIdx.x;
  const float4 v = ((const float4*)rp)[t];
  float mx = fmaxf(fmaxf(v.x, v.y), fmaxf(v.z, v.w));
#pragma unroll
  for (int o = 32; o; o >>= 1) mx = fmaxf(mx, __shfl_xor(mx, o));
  __shared__ float red[8];
  const int w = t >> 6, ln = t & 63;
  if (ln == 0) red[w] = mx;
  __syncthreads();
  mx = fmaxf(fmaxf(red[0], red[1]), fmaxf(red[2], red[3]));
  const float e0 = __expf(v.x - mx), e1 = __expf(v.y - mx);
  const float e2 = __expf(v.z - mx), e3 = __expf(v.w - mx);
  float sm = (e0 + e1) + (e2 + e3);
#pragma unroll
  for (int o = 32; o; o >>= 1) sm += __shfl_xor(sm, o);
  if (ln == 0) red[4 + w] = sm;
  __syncthreads();
  const float inv = 1.0f / ((red[4] + red[5]) + (red[6] + red[7]));
  bf16* op = (bf16*)rp;  // all reads of this row happened before first barrier
  op[4 * t + 0] = __float2bfloat16(e0 * inv);
  op[4 * t + 1] = __float2bfloat16(e1 * inv);
  op[4 * t + 2] = __float2bfloat16(e2 * inv);
  op[4 * t + 3] = __float2bfloat16(e3 * inv);
}

// ---------------- attn = P @ V per (chunk,head); N=96 (24 pad) ------------
__global__ __launch_bounds__(256, 2)
void k_pv(const bf16* __restrict__ P, const bf16* __restrict__ Vt,
          bf16* __restrict__ Jb, int s0) {
  __shared__ bf16 sA[128 * 32], sB[96 * 32];
  const int w = threadIdx.x >> 6, ln = threadIdx.x & 63;
  const int h = blockIdx.y;
  const int m0 = blockIdx.x * 128;
  const bf16* A = P + ((size_t)h * CLEN + m0) * 2048;  // probs, stride 2048
  const bf16* B = Vt + (size_t)h * HDP * S_TOT + s0;
  const int r = ln & 15, g = ln >> 4;
  const int wr = (w >> 1) * 64, wc = (w & 1) * 48;
  f32x4 acc[4][3] = {};
  for (int k0 = 0; k0 < CLEN; k0 += 32) {
    __syncthreads();
    stage128x32(A + k0, 2048, sA, w, ln);
#pragma unroll
    for (int c = 0; c < 2; ++c) {  // 96x32 tile: 6 wave-calls
      const int call = w + c * 4;
      if (call < 6) {
        const int f = (call * 64 + ln) * 8;
        gld_lds16(B + (size_t)(f >> 5) * S_TOT + k0 + (f & 31), sB + call * 512);
      }
    }
    __syncthreads();
    bf16x8 a[4];
#pragma unroll
    for (int m = 0; m < 4; ++m)
      a[m] = *(const bf16x8*)&sA[(wr + m * 16 + r) * 32 + g * 8];
#pragma unroll
    for (int n = 0; n < 3; ++n) {
      bf16x8 bv = *(const bf16x8*)&sB[(wc + n * 16 + r) * 32 + g * 8];
#pragma unroll
      for (int m = 0; m < 4; ++m)
        acc[m][n] = __builtin_amdgcn_mfma_f32_16x16x32_bf16(a[m], bv, acc[m][n], 0, 0, 0);
    }
  }
#pragma unroll
  for (int n = 0; n < 3; ++n) {
    const int d = wc + n * 16 + r;
    if (d < HD) {
#pragma unroll
      for (int m = 0; m < 4; ++m)
#pragma unroll
        for (int j = 0; j < 4; ++j) {
          const int srow = s0 + m0 + wr + m * 16 + g * 4 + j;
          Jb[(size_t)srow * E_DIM + h * HD + d] = __float2bfloat16(acc[m][n][j]);
        }
    }
  }
}

// ---------------- out = attn @ proj_w^T + proj_b (plain bf16) -------------
__global__ __launch_bounds__(256, 2)
void k_proj(const bf16* __restrict__ Jb, const bf16* __restrict__ Pw,
            const float* __restrict__ bias, float* __restrict__ out) {
  __shared__ bf16 sA[128 * 32], sB[128 * 32];
  const int w = threadIdx.x >> 6, ln = threadIdx.x & 63;
  const int m0 = blockIdx.x * 128, n0 = blockIdx.y * 128;
  const bf16* A = Jb + (size_t)m0 * E_DIM;
  const bf16* B = Pw + (size_t)n0 * E_DIM;
  const int r = ln & 15, g = ln >> 4;
  const int wr = (w >> 1) * 64, wc = (w & 1) * 64;
  f32x4 acc[4][4] = {};
  for (int k0 = 0; k0 < E_DIM; k0 += 32) {
    __syncthreads();
    stage128x32(A + k0, E_DIM, sA, w, ln);
    stage128x32(B + k0, E_DIM, sB, w, ln);
    __syncthreads();
    bf16x8 a[4];
#pragma unroll
    for (int m = 0; m < 4; ++m)
      a[m] = *(const bf16x8*)&sA[(wr + m * 16 + r) * 32 + g * 8];
#pragma unroll
    for (int n = 0; n < 4; ++n) {
      bf16x8 bv = *(const bf16x8*)&sB[(wc + n * 16 + r) * 32 + g * 8];
#pragma unroll
      for (int m = 0; m < 4; ++m)
        acc[m][n] = __builtin_amdgcn_mfma_f32_16x16x32_bf16(a[m], bv, acc[m][n], 0, 0, 0);
    }
  }
#pragma unroll
  for (int n = 0; n < 4; ++n) {
    const int col = n0 + wc + n * 16 + r;
    const float bv = bias[col];
#pragma unroll
    for (int m = 0; m < 4; ++m)
#pragma unroll
      for (int j = 0; j < 4; ++j) {
        const int row = m0 + wr + m * 16 + g * 4 + j;
        out[(size_t)row * E_DIM + col] = acc[m][n][j] + bv;
      }
  }
}

// --------------------------------- launch ---------------------------------
extern "C" void kernel_launch(void* const* d_in, const int* in_sizes, int n_in,
                              void* d_out, int out_size, void* d_ws, size_t ws_size,
                              hipStream_t stream) {
  (void)in_sizes; (void)n_in; (void)out_size; (void)ws_size;
  const float* hs   = (const float*)d_in[0];
  const float* cosp = (const float*)d_in[1];
  const float* sinp = (const float*)d_in[2];
  const float* qkvw = (const float*)d_in[3];
  const float* qkvb = (const float*)d_in[4];
  const float* pw   = (const float*)d_in[5];
  const float* pb   = (const float*)d_in[6];
  float* out = (float*)d_out;
  char* ws = (char*)d_ws;

  // Workspace layout (bytes). [0, 82.0M) is dead before the chunk loop and is
  // reused for the per-chunk scores/probs buffer (67.1M).
  float* Eq  = (float*)(ws + 0);          // 4096x1152 f32   (q pre-RoPE)
  float* Ek  = (float*)(ws + 18874368);   // 4096x1152 f32   (k pre-RoPE)
  bf16*  Ahi = (bf16*)(ws + 37748736);    // hs hi
  bf16*  Alo = (bf16*)(ws + 47185920);    // hs lo
  bf16*  Whi = (bf16*)(ws + 56623104);    // qkv_w hi
  bf16*  Wlo = (bf16*)(ws + 64585728);    // qkv_w lo
  bf16*  Vb  = (bf16*)(ws + 72548352);    // v row-major bf16
  float* Sc  = (float*)(ws + 0);          // scores/probs per chunk (REUSE)
  bf16*  Qb  = (bf16*)(ws + 81985536);    // q bf16 [4096][16][96]
  bf16*  Kb  = (bf16*)(ws + 94568448);    // k bf16 [4096][16][96]
  bf16*  Vt  = (bf16*)(ws + 107151360);   // v^T bf16 [16][96][4096]
  bf16*  Jb  = (bf16*)(ws + 119734272);   // attn bf16 [4096][1152]
  bf16*  Pw  = (bf16*)(ws + 129171456);   // proj_w bf16
  // total 131825664 bytes (~126 MiB)

  // zero Qb,Kb,Vt (contiguous) so the D->96 pad columns/rows are exact zeros
  hipMemsetAsync(ws + 81985536, 0, 37748736, stream);

  k_pack_split<<<4608, 256, 0, stream>>>(hs, Ahi, Alo);
  k_pack_split<<<3888, 256, 0, stream>>>(qkvw, Whi, Wlo);
  k_pack_plain<<<1296, 256, 0, stream>>>(pw, Pw);
  k_qkv_gemm<<<dim3(32, 27), 256, 0, stream>>>(Ahi, Alo, Whi, Wlo, qkvb, Eq, Ek, Vb);
  k_vtrans<<<dim3(36, 128), dim3(32, 8), 0, stream>>>(Vb, Vt);
  k_rope<<<9216, 256, 0, stream>>>(Eq, Ek, cosp, sinp, Qb, Kb);

  for (int b = 0; b < 4; ++b) {
    const int s0 = b * CLEN;
    k_qk<<<dim3(8, 8, 16), 256, 0, stream>>>(Qb, Kb, Sc, s0);
    k_softmax<<<16384, 256, 0, stream>>>(Sc);
    k_pv<<<dim3(8, 16), 256, 0, stream>>>((const bf16*)Sc, Vt, Jb, s0);
  }
  k_proj<<<dim3(32, 9), 256, 0, stream>>>(Jb, Pw, pb, out);
}

// Round 4
// 328.815 us; speedup vs baseline: 1.4719x; 1.4719x over previous
//
#include <hip/hip_runtime.h>
#include <hip/hip_bf16.h>

// Qwen3VL vision attention, MI355X. Round 4: flash attention with P
// redistribution via plain swizzled LDS round-trip (tr_read removed — its
// per-lane address semantics were the prime suspect for R2/R3's absmax~0.45).
// Keeps R3's per-component online-softmax rescale fix.

#define S_TOT 4096
#define E_DIM 1152
#define NH    16
#define HD    72
#define HDP   96      // D padded to 96 for uniform K-steps of 32
#define CLEN  1024

static constexpr float SCALE_QK = 0.11785113019775793f;  // 72^-0.5

typedef __bf16 bf16x8 __attribute__((ext_vector_type(8)));
typedef float  f32x4  __attribute__((ext_vector_type(4)));
typedef __hip_bfloat16 bf16;

// ---- async global->LDS, 16B per lane; LDS dest must be wave-uniform ----
__device__ __forceinline__ void gld_lds16(const void* g, void* l) {
  __builtin_amdgcn_global_load_lds(
      (const __attribute__((address_space(1))) unsigned int*)g,
      (__attribute__((address_space(3))) unsigned int*)l, 16, 0, 0);
}

// Stage a 128x32 bf16 tile (row-major, row stride ld elements) into LDS.
__device__ __forceinline__ void stage128x32(const bf16* src, int ld, bf16* dst,
                                            int w, int ln) {
#pragma unroll
  for (int c = 0; c < 2; ++c) {
    const int f = ((w * 2 + c) * 64 + ln) * 8;       // flat bf16 idx in tile
    gld_lds16(src + (f >> 5) * ld + (f & 31), dst + (w * 2 + c) * 512);
  }
}

// Stage a 128x96 CONTIGUOUS bf16 tile into LDS [128][96], granule swizzle
// c' = c ^ (row&3) (bijective within aligned 4-granule blocks of the
// 12-granule row). Readers must apply the same XOR.
__device__ __forceinline__ void stage128x96(const bf16* src, bf16* dst,
                                            int w, int ln) {
#pragma unroll
  for (int j = 0; j < 6; ++j) {
    const int f = (w * 6 + j) * 64 + ln;             // granule index [0,1536)
    const int row = f / 12, c = f % 12;
    gld_lds16(src + row * 96 + ((c ^ (row & 3)) << 3), dst + f * 8);
  }
}

// Stage a 96x128 tile from Vt (row stride 4096) into LDS [96][128],
// granule swizzle c' = c ^ (d&7).
__device__ __forceinline__ void stageVt(const bf16* src, bf16* dst,
                                        int w, int ln) {
#pragma unroll
  for (int j = 0; j < 6; ++j) {
    const int f = (w * 6 + j) * 64 + ln;             // granule index [0,1536)
    const int d = f >> 4, c = f & 15;
    gld_lds16(src + (size_t)d * S_TOT + ((c ^ (d & 7)) << 3), dst + f * 8);
  }
}

// ---------------- pack fp32 -> bf16 (hi) and residual (lo) ----------------
__global__ void k_pack_split(const float* __restrict__ x, bf16* __restrict__ hi,
                             bf16* __restrict__ lo) {
  const int i = blockIdx.x * blockDim.x + threadIdx.x;
  const float4 v = ((const float4*)x)[i];
  const float f0 = v.x, f1 = v.y, f2 = v.z, f3 = v.w;
  bf16 h0 = __float2bfloat16(f0), h1 = __float2bfloat16(f1);
  bf16 h2 = __float2bfloat16(f2), h3 = __float2bfloat16(f3);
  hi[4 * i + 0] = h0; hi[4 * i + 1] = h1; hi[4 * i + 2] = h2; hi[4 * i + 3] = h3;
  lo[4 * i + 0] = __float2bfloat16(f0 - __bfloat162float(h0));
  lo[4 * i + 1] = __float2bfloat16(f1 - __bfloat162float(h1));
  lo[4 * i + 2] = __float2bfloat16(f2 - __bfloat162float(h2));
  lo[4 * i + 3] = __float2bfloat16(f3 - __bfloat162float(h3));
}

__global__ void k_pack_plain(const float* __restrict__ x, bf16* __restrict__ y) {
  const int i = blockIdx.x * blockDim.x + threadIdx.x;
  const float4 v = ((const float4*)x)[i];
  y[4 * i + 0] = __float2bfloat16(v.x);
  y[4 * i + 1] = __float2bfloat16(v.y);
  y[4 * i + 2] = __float2bfloat16(v.z);
  y[4 * i + 3] = __float2bfloat16(v.w);
}

// ---------------- QKV GEMM, split-bf16 (3 MFMAs per fragment) -------------
__global__ __launch_bounds__(256, 2)
void k_qkv_gemm(const bf16* __restrict__ Ahi, const bf16* __restrict__ Alo,
                const bf16* __restrict__ Whi, const bf16* __restrict__ Wlo,
                const float* __restrict__ bias, float* __restrict__ Eq,
                float* __restrict__ Ek, bf16* __restrict__ Vb) {
  __shared__ bf16 sAh[128 * 32], sAl[128 * 32], sBh[128 * 32], sBl[128 * 32];
  const int w = threadIdx.x >> 6, ln = threadIdx.x & 63;
  const int m0 = blockIdx.x * 128, n0 = blockIdx.y * 128;
  const bf16* Ah = Ahi + (size_t)m0 * E_DIM;
  const bf16* Al = Alo + (size_t)m0 * E_DIM;
  const bf16* Bh = Whi + (size_t)n0 * E_DIM;
  const bf16* Bl = Wlo + (size_t)n0 * E_DIM;
  const int r = ln & 15, g = ln >> 4;
  const int wr = (w >> 1) * 64, wc = (w & 1) * 64;
  f32x4 acc[4][4] = {};
  for (int k0 = 0; k0 < E_DIM; k0 += 32) {
    __syncthreads();
    stage128x32(Ah + k0, E_DIM, sAh, w, ln);
    stage128x32(Al + k0, E_DIM, sAl, w, ln);
    stage128x32(Bh + k0, E_DIM, sBh, w, ln);
    stage128x32(Bl + k0, E_DIM, sBl, w, ln);
    __syncthreads();
    bf16x8 ah[4], al[4];
#pragma unroll
    for (int m = 0; m < 4; ++m) {
      ah[m] = *(const bf16x8*)&sAh[(wr + m * 16 + r) * 32 + g * 8];
      al[m] = *(const bf16x8*)&sAl[(wr + m * 16 + r) * 32 + g * 8];
    }
#pragma unroll
    for (int n = 0; n < 4; ++n) {
      bf16x8 bh = *(const bf16x8*)&sBh[(wc + n * 16 + r) * 32 + g * 8];
      bf16x8 bl = *(const bf16x8*)&sBl[(wc + n * 16 + r) * 32 + g * 8];
#pragma unroll
      for (int m = 0; m < 4; ++m) {
        acc[m][n] = __builtin_amdgcn_mfma_f32_16x16x32_bf16(ah[m], bh, acc[m][n], 0, 0, 0);
        acc[m][n] = __builtin_amdgcn_mfma_f32_16x16x32_bf16(al[m], bh, acc[m][n], 0, 0, 0);
        acc[m][n] = __builtin_amdgcn_mfma_f32_16x16x32_bf16(ah[m], bl, acc[m][n], 0, 0, 0);
      }
    }
  }
  const int sect = n0 / E_DIM;  // 128-col tile lies fully in one of q/k/v
#pragma unroll
  for (int n = 0; n < 4; ++n) {
    const int col = n0 + wc + n * 16 + r;
    const float bv = bias[col];
    const int cl = col - sect * E_DIM;
#pragma unroll
    for (int m = 0; m < 4; ++m)
#pragma unroll
      for (int j = 0; j < 4; ++j) {
        const int row = m0 + wr + m * 16 + g * 4 + j;
        const float v = acc[m][n][j] + bv;
        if (sect == 0)      Eq[(size_t)row * E_DIM + cl] = v;
        else if (sect == 1) Ek[(size_t)row * E_DIM + cl] = v;
        else                Vb[(size_t)row * E_DIM + cl] = __float2bfloat16(v);
      }
  }
}

// ---------------- V transpose: Vb[s][h*72+d] -> Vt[h][d(96)][s] -----------
__global__ void k_vtrans(const bf16* __restrict__ Vb, bf16* __restrict__ Vt) {
  __shared__ bf16 t[32][33];
  const int hd0 = blockIdx.x * 32, s0 = blockIdx.y * 32;
  const int tx = threadIdx.x, ty = threadIdx.y;  // 32 x 8
#pragma unroll
  for (int k = 0; k < 4; ++k)
    t[ty + 8 * k][tx] = Vb[(size_t)(s0 + ty + 8 * k) * E_DIM + hd0 + tx];
  __syncthreads();
#pragma unroll
  for (int k = 0; k < 4; ++k) {
    const int hd = hd0 + ty + 8 * k;
    const int hh = hd / HD, dd = hd % HD;
    Vt[((size_t)hh * HDP + dd) * S_TOT + s0 + tx] = t[tx][ty + 8 * k];
  }
}

// ------- RoPE fp32 -> bf16 q,k in head-major [h][s][96]; q pre-scaled -----
__global__ void k_rope(const float* __restrict__ Eq, const float* __restrict__ Ek,
                       const float* __restrict__ cs, const float* __restrict__ sn,
                       bf16* __restrict__ Qh, bf16* __restrict__ Kh) {
  const int i = blockIdx.x * 256 + threadIdx.x;  // over 4096*16*48
  const int d = i % 48;
  const int h = (i / 48) & 15;
  const int s = i / (48 * 16);
  const size_t ob = ((size_t)h * S_TOT + s) * HDP;
  if (d >= 36) {
    const int z = d - 36;
    const bf16 zero = __float2bfloat16(0.f);
    Qh[ob + 72 + z] = zero; Qh[ob + 84 + z] = zero;
    Kh[ob + 72 + z] = zero; Kh[ob + 84 + z] = zero;
    return;
  }
  const float c0 = cs[s * HD + d], s0 = sn[s * HD + d];
  const float c1 = cs[s * HD + d + 36], s1 = sn[s * HD + d + 36];
  const size_t qi = (size_t)s * E_DIM + h * HD;
  {
    const float x0 = Eq[qi + d], x1 = Eq[qi + d + 36];
    Qh[ob + d]      = __float2bfloat16((x0 * c0 - x1 * s0) * SCALE_QK);
    Qh[ob + d + 36] = __float2bfloat16((x1 * c1 + x0 * s1) * SCALE_QK);
  }
  {
    const float x0 = Ek[qi + d], x1 = Ek[qi + d + 36];
    Kh[ob + d]      = __float2bfloat16(x0 * c0 - x1 * s0);
    Kh[ob + d + 36] = __float2bfloat16(x1 * c1 + x0 * s1);
  }
}

// ---------------- flash attention: one (chunk,head,q-tile of 128) ---------
// 4 waves x 32 q-rows. Online softmax in registers. P redistribution:
// per-wave LDS plane [m=2][q=16][kv=128] bf16, granule (8 bf16) XOR-swizzled
// by (q&7); written scalar from the C-layout, read as bf16x8 A-fragments.
__global__ __launch_bounds__(256, 2)
void k_flash(const bf16* __restrict__ Qh, const bf16* __restrict__ Kh,
             const bf16* __restrict__ Vt, bf16* __restrict__ Jb) {
  __shared__ bf16 sK[128 * 96];    // 24 KB, [kv][96] swizzled c^=(kv&3)
  __shared__ bf16 sV[96 * 128];    // 24 KB, [d][128] swizzled c^=(d&7)
  __shared__ bf16 sP[4 * 4096];    // 32 KB: P planes (8KB/wave); doubles as sQ
  const int w = threadIdx.x >> 6, ln = threadIdx.x & 63;
  const int r = ln & 15, g = ln >> 4;
  const int h = blockIdx.y, s0 = blockIdx.z * CLEN;
  const int q0 = blockIdx.x * 128;
  const bf16* Qg = Qh + ((size_t)h * S_TOT + s0 + q0) * HDP;
  const bf16* Kg = Kh + ((size_t)h * S_TOT + s0) * HDP;
  const bf16* Vg = Vt + (size_t)h * HDP * S_TOT + s0;

  // Q tile -> sP region, then Q fragments to registers (once).
  stage128x96(Qg, sP, w, ln);
  __syncthreads();
  const char* sPb = (const char*)sP;
  bf16x8 qa[2][3];
#pragma unroll
  for (int m = 0; m < 2; ++m)
#pragma unroll
    for (int ks = 0; ks < 3; ++ks) {
      const int row = w * 32 + m * 16 + r;
      qa[m][ks] = *(const bf16x8*)(sPb + row * 192 + (((ks * 4 + g) ^ (row & 3)) << 4));
    }

  f32x4 oacc[2][6] = {};
  float mrun[2][4], lrun[2][4];
#pragma unroll
  for (int m = 0; m < 2; ++m)
#pragma unroll
    for (int j = 0; j < 4; ++j) { mrun[m][j] = -1e30f; lrun[m][j] = 0.f; }

  char* sPw = (char*)sP + w * 8192;
  const char* sKb = (const char*)sK;
  const char* sVb = (const char*)sV;

  for (int t = 0; t < 8; ++t) {
    __syncthreads();                       // prev tile consumed / qa loaded
    stage128x96(Kg + t * 128 * HDP, sK, w, ln);
    stageVt(Vg + t * 128, sV, w, ln);
    __syncthreads();                       // staging complete

    // ---- QK^T: acc[m][n][j] = S[q=w*32+m*16+g*4+j][kv=n*16+r] ----
    f32x4 acc[2][8] = {};
#pragma unroll
    for (int ks = 0; ks < 3; ++ks)
#pragma unroll
      for (int n = 0; n < 8; ++n) {
        const int kv = n * 16 + r;
        bf16x8 bv = *(const bf16x8*)(sKb + kv * 192 + (((ks * 4 + g) ^ (kv & 3)) << 4));
        acc[0][n] = __builtin_amdgcn_mfma_f32_16x16x32_bf16(qa[0][ks], bv, acc[0][n], 0, 0, 0);
        acc[1][n] = __builtin_amdgcn_mfma_f32_16x16x32_bf16(qa[1][ks], bv, acc[1][n], 0, 0, 0);
      }

    // ---- online softmax per row (m,j); 16 lanes of group g share rows ----
#pragma unroll
    for (int m = 0; m < 2; ++m)
#pragma unroll
      for (int j = 0; j < 4; ++j) {
        float tm = acc[m][0][j];
#pragma unroll
        for (int n = 1; n < 8; ++n) tm = fmaxf(tm, acc[m][n][j]);
#pragma unroll
        for (int o = 1; o < 16; o <<= 1) tm = fmaxf(tm, __shfl_xor(tm, o));
        const float mn = fmaxf(mrun[m][j], tm);
        const float esc = __expf(mrun[m][j] - mn);
        mrun[m][j] = mn;
        float sm = 0.f;
#pragma unroll
        for (int n = 0; n < 8; ++n) {
          const float p = __expf(acc[m][n][j] - mn);
          acc[m][n][j] = p; sm += p;
        }
#pragma unroll
        for (int o = 1; o < 16; o <<= 1) sm += __shfl_xor(sm, o);
        lrun[m][j] = lrun[m][j] * esc + sm;
#pragma unroll
        for (int n = 0; n < 6; ++n) oacc[m][n][j] *= esc;  // per-component
      }

    // ---- P -> per-wave plane [m][q=16][kv=128], granule ^= (q&7) ----
    // Element (q,kv) at byte q*256 + (((kv>>3)^(q&7))<<4) + (kv&7)*2.
#pragma unroll
    for (int m = 0; m < 2; ++m)
#pragma unroll
      for (int n = 0; n < 8; ++n) {
        const int kv = n * 16 + r;
        const int gr = kv >> 3, wi = kv & 7;
#pragma unroll
        for (int j = 0; j < 4; ++j) {
          const int q = g * 4 + j;
          *(bf16*)(sPw + m * 4096 + q * 256 + ((gr ^ (q & 7)) << 4) + wi * 2) =
              __float2bfloat16(acc[m][n][j]);
        }
      }

    // ---- PV: O[q][d] += P[q][kv] V[kv][d]; A-frags = plane row r ----
#pragma unroll
    for (int ks = 0; ks < 4; ++ks) {
      bf16x8 pa[2];
#pragma unroll
      for (int m = 0; m < 2; ++m)
        pa[m] = *(const bf16x8*)(sPw + m * 4096 + r * 256 +
                                 (((ks * 4 + g) ^ (r & 7)) << 4));
#pragma unroll
      for (int n = 0; n < 6; ++n) {
        const int d = n * 16 + r;
        bf16x8 vb = *(const bf16x8*)(sVb + d * 256 + (((ks * 4 + g) ^ (d & 7)) << 4));
        oacc[0][n] = __builtin_amdgcn_mfma_f32_16x16x32_bf16(pa[0], vb, oacc[0][n], 0, 0, 0);
        oacc[1][n] = __builtin_amdgcn_mfma_f32_16x16x32_bf16(pa[1], vb, oacc[1][n], 0, 0, 0);
      }
    }
  }

  // ---- epilogue: O /= l, write Jb[s][h*72+d] for d<72 ----
#pragma unroll
  for (int m = 0; m < 2; ++m) {
    float inv[4];
#pragma unroll
    for (int j = 0; j < 4; ++j) inv[j] = 1.0f / lrun[m][j];
#pragma unroll
    for (int n = 0; n < 6; ++n) {
      const int d = n * 16 + r;
      if (d < HD) {
#pragma unroll
        for (int j = 0; j < 4; ++j) {
          const int row = s0 + q0 + w * 32 + m * 16 + g * 4 + j;
          Jb[(size_t)row * E_DIM + h * HD + d] = __float2bfloat16(oacc[m][n][j] * inv[j]);
        }
      }
    }
  }
}

// ---------------- out = attn @ proj_w^T + proj_b (plain bf16) -------------
__global__ __launch_bounds__(256, 2)
void k_proj(const bf16* __restrict__ Jb, const bf16* __restrict__ Pw,
            const float* __restrict__ bias, float* __restrict__ out) {
  __shared__ bf16 sA[128 * 32], sB[128 * 32];
  const int w = threadIdx.x >> 6, ln = threadIdx.x & 63;
  const int m0 = blockIdx.x * 128, n0 = blockIdx.y * 128;
  const bf16* A = Jb + (size_t)m0 * E_DIM;
  const bf16* B = Pw + (size_t)n0 * E_DIM;
  const int r = ln & 15, g = ln >> 4;
  const int wr = (w >> 1) * 64, wc = (w & 1) * 64;
  f32x4 acc[4][4] = {};
  for (int k0 = 0; k0 < E_DIM; k0 += 32) {
    __syncthreads();
    stage128x32(A + k0, E_DIM, sA, w, ln);
    stage128x32(B + k0, E_DIM, sB, w, ln);
    __syncthreads();
    bf16x8 a[4];
#pragma unroll
    for (int m = 0; m < 4; ++m)
      a[m] = *(const bf16x8*)&sA[(wr + m * 16 + r) * 32 + g * 8];
#pragma unroll
    for (int n = 0; n < 4; ++n) {
      bf16x8 bv = *(const bf16x8*)&sB[(wc + n * 16 + r) * 32 + g * 8];
#pragma unroll
      for (int m = 0; m < 4; ++m)
        acc[m][n] = __builtin_amdgcn_mfma_f32_16x16x32_bf16(a[m], bv, acc[m][n], 0, 0, 0);
    }
  }
#pragma unroll
  for (int n = 0; n < 4; ++n) {
    const int col = n0 + wc + n * 16 + r;
    const float bv = bias[col];
#pragma unroll
    for (int m = 0; m < 4; ++m)
#pragma unroll
      for (int j = 0; j < 4; ++j) {
        const int row = m0 + wr + m * 16 + g * 4 + j;
        out[(size_t)row * E_DIM + col] = acc[m][n][j] + bv;
      }
  }
}

// --------------------------------- launch ---------------------------------
extern "C" void kernel_launch(void* const* d_in, const int* in_sizes, int n_in,
                              void* d_out, int out_size, void* d_ws, size_t ws_size,
                              hipStream_t stream) {
  (void)in_sizes; (void)n_in; (void)out_size; (void)ws_size;
  const float* hs   = (const float*)d_in[0];
  const float* cosp = (const float*)d_in[1];
  const float* sinp = (const float*)d_in[2];
  const float* qkvw = (const float*)d_in[3];
  const float* qkvb = (const float*)d_in[4];
  const float* pw   = (const float*)d_in[5];
  const float* pb   = (const float*)d_in[6];
  float* out = (float*)d_out;
  char* ws = (char*)d_ws;

  float* Eq  = (float*)(ws + 0);          // 4096x1152 f32   (q pre-RoPE)
  float* Ek  = (float*)(ws + 18874368);   // 4096x1152 f32   (k pre-RoPE)
  bf16*  Ahi = (bf16*)(ws + 37748736);    // hs hi
  bf16*  Alo = (bf16*)(ws + 47185920);    // hs lo
  bf16*  Whi = (bf16*)(ws + 56623104);    // qkv_w hi
  bf16*  Wlo = (bf16*)(ws + 64585728);    // qkv_w lo
  bf16*  Vb  = (bf16*)(ws + 72548352);    // v row-major bf16
  bf16*  Qh  = (bf16*)(ws + 81985536);    // q bf16 [16][4096][96], scaled
  bf16*  Kh  = (bf16*)(ws + 94568448);    // k bf16 [16][4096][96]
  bf16*  Vt  = (bf16*)(ws + 107151360);   // v^T bf16 [16][96][4096]
  bf16*  Jb  = (bf16*)(ws + 119734272);   // attn bf16 [4096][1152]
  bf16*  Pw  = (bf16*)(ws + 129171456);   // proj_w bf16
  // total 131825664 bytes (~126 MiB)

  // Vt zero so pad rows d=72..95 are exact zeros
  hipMemsetAsync(ws + 107151360, 0, 12582912, stream);

  k_pack_split<<<4608, 256, 0, stream>>>(hs, Ahi, Alo);
  k_pack_split<<<3888, 256, 0, stream>>>(qkvw, Whi, Wlo);
  k_pack_plain<<<1296, 256, 0, stream>>>(pw, Pw);
  k_qkv_gemm<<<dim3(32, 27), 256, 0, stream>>>(Ahi, Alo, Whi, Wlo, qkvb, Eq, Ek, Vb);
  k_vtrans<<<dim3(36, 128), dim3(32, 8), 0, stream>>>(Vb, Vt);
  k_rope<<<12288, 256, 0, stream>>>(Eq, Ek, cosp, sinp, Qh, Kh);
  k_flash<<<dim3(8, 16, 4), 256, 0, stream>>>(Qh, Kh, Vt, Jb);
  k_proj<<<dim3(32, 9), 256, 0, stream>>>(Jb, Pw, pb, out);
}

// Round 5
// 249.589 us; speedup vs baseline: 1.9391x; 1.3174x over previous
//
#include <hip/hip_runtime.h>
#include <hip/hip_bf16.h>

// Qwen3VL vision attention, MI355X. Round 5: plain-bf16 QKV GEMM (1 MFMA; the
// 3-MFMA split was precision overkill — softmax damps scores error by ~0.05x),
// fused QKV bf16 output buffer, bf16 RoPE input. Flash kernel unchanged (R4).

#define S_TOT 4096
#define E_DIM 1152
#define QKV_N 3456
#define NH    16
#define HD    72
#define HDP   96      // D padded to 96 for uniform K-steps of 32
#define CLEN  1024

static constexpr float SCALE_QK = 0.11785113019775793f;  // 72^-0.5

typedef __bf16 bf16x8 __attribute__((ext_vector_type(8)));
typedef float  f32x4  __attribute__((ext_vector_type(4)));
typedef __hip_bfloat16 bf16;

// ---- async global->LDS, 16B per lane; LDS dest must be wave-uniform ----
__device__ __forceinline__ void gld_lds16(const void* g, void* l) {
  __builtin_amdgcn_global_load_lds(
      (const __attribute__((address_space(1))) unsigned int*)g,
      (__attribute__((address_space(3))) unsigned int*)l, 16, 0, 0);
}

// Stage a 128x32 bf16 tile (row-major, row stride ld elements) into LDS.
__device__ __forceinline__ void stage128x32(const bf16* src, int ld, bf16* dst,
                                            int w, int ln) {
#pragma unroll
  for (int c = 0; c < 2; ++c) {
    const int f = ((w * 2 + c) * 64 + ln) * 8;       // flat bf16 idx in tile
    gld_lds16(src + (f >> 5) * ld + (f & 31), dst + (w * 2 + c) * 512);
  }
}

// Stage a 128x96 CONTIGUOUS bf16 tile into LDS [128][96], granule swizzle
// c' = c ^ (row&3). Readers must apply the same XOR.
__device__ __forceinline__ void stage128x96(const bf16* src, bf16* dst,
                                            int w, int ln) {
#pragma unroll
  for (int j = 0; j < 6; ++j) {
    const int f = (w * 6 + j) * 64 + ln;             // granule index [0,1536)
    const int row = f / 12, c = f % 12;
    gld_lds16(src + row * 96 + ((c ^ (row & 3)) << 3), dst + f * 8);
  }
}

// Stage a 96x128 tile from Vt (row stride 4096) into LDS [96][128],
// granule swizzle c' = c ^ (d&7).
__device__ __forceinline__ void stageVt(const bf16* src, bf16* dst,
                                        int w, int ln) {
#pragma unroll
  for (int j = 0; j < 6; ++j) {
    const int f = (w * 6 + j) * 64 + ln;             // granule index [0,1536)
    const int d = f >> 4, c = f & 15;
    gld_lds16(src + (size_t)d * S_TOT + ((c ^ (d & 7)) << 3), dst + f * 8);
  }
}

// ---------------- pack fp32 -> bf16 ----------------
__global__ void k_pack_plain(const float* __restrict__ x, bf16* __restrict__ y) {
  const int i = blockIdx.x * blockDim.x + threadIdx.x;
  const float4 v = ((const float4*)x)[i];
  y[4 * i + 0] = __float2bfloat16(v.x);
  y[4 * i + 1] = __float2bfloat16(v.y);
  y[4 * i + 2] = __float2bfloat16(v.z);
  y[4 * i + 3] = __float2bfloat16(v.w);
}

// ---------------- QKV GEMM, plain bf16 -------------
// QKVb[4096,3456] = hs @ qkv_w^T + b  (bf16 out, fp32 accum)
__global__ __launch_bounds__(256, 2)
void k_qkv_gemm(const bf16* __restrict__ Ab, const bf16* __restrict__ Wb,
                const float* __restrict__ bias, bf16* __restrict__ C) {
  __shared__ bf16 sA[128 * 32], sB[128 * 32];
  const int w = threadIdx.x >> 6, ln = threadIdx.x & 63;
  const int m0 = blockIdx.x * 128, n0 = blockIdx.y * 128;
  const bf16* A = Ab + (size_t)m0 * E_DIM;
  const bf16* B = Wb + (size_t)n0 * E_DIM;
  const int r = ln & 15, g = ln >> 4;
  const int wr = (w >> 1) * 64, wc = (w & 1) * 64;
  f32x4 acc[4][4] = {};
  for (int k0 = 0; k0 < E_DIM; k0 += 32) {
    __syncthreads();
    stage128x32(A + k0, E_DIM, sA, w, ln);
    stage128x32(B + k0, E_DIM, sB, w, ln);
    __syncthreads();
    bf16x8 a[4];
#pragma unroll
    for (int m = 0; m < 4; ++m)
      a[m] = *(const bf16x8*)&sA[(wr + m * 16 + r) * 32 + g * 8];
#pragma unroll
    for (int n = 0; n < 4; ++n) {
      bf16x8 bv = *(const bf16x8*)&sB[(wc + n * 16 + r) * 32 + g * 8];
#pragma unroll
      for (int m = 0; m < 4; ++m)
        acc[m][n] = __builtin_amdgcn_mfma_f32_16x16x32_bf16(a[m], bv, acc[m][n], 0, 0, 0);
    }
  }
#pragma unroll
  for (int n = 0; n < 4; ++n) {
    const int col = n0 + wc + n * 16 + r;
    const float bv = bias[col];
#pragma unroll
    for (int m = 0; m < 4; ++m)
#pragma unroll
      for (int j = 0; j < 4; ++j) {
        const int row = m0 + wr + m * 16 + g * 4 + j;
        C[(size_t)row * QKV_N + col] = __float2bfloat16(acc[m][n][j] + bv);
      }
  }
}

// ---- V transpose: QKVb[s][2304 + h*72+d] -> Vt[h][d(96)][s] ----
__global__ void k_vtrans(const bf16* __restrict__ Qkv, bf16* __restrict__ Vt) {
  __shared__ bf16 t[32][33];
  const int hd0 = blockIdx.x * 32, s0 = blockIdx.y * 32;
  const int tx = threadIdx.x, ty = threadIdx.y;  // 32 x 8
#pragma unroll
  for (int k = 0; k < 4; ++k)
    t[ty + 8 * k][tx] = Qkv[(size_t)(s0 + ty + 8 * k) * QKV_N + 2304 + hd0 + tx];
  __syncthreads();
#pragma unroll
  for (int k = 0; k < 4; ++k) {
    const int hd = hd0 + ty + 8 * k;
    const int hh = hd / HD, dd = hd % HD;
    Vt[((size_t)hh * HDP + dd) * S_TOT + s0 + tx] = t[tx][ty + 8 * k];
  }
}

// ------- RoPE bf16 -> bf16 q,k in head-major [h][s][96]; q pre-scaled -----
__global__ void k_rope(const bf16* __restrict__ Qkv,
                       const float* __restrict__ cs, const float* __restrict__ sn,
                       bf16* __restrict__ Qh, bf16* __restrict__ Kh) {
  const int i = blockIdx.x * 256 + threadIdx.x;  // over 4096*16*48
  const int d = i % 48;
  const int h = (i / 48) & 15;
  const int s = i / (48 * 16);
  const size_t ob = ((size_t)h * S_TOT + s) * HDP;
  if (d >= 36) {
    const int z = d - 36;
    const bf16 zero = __float2bfloat16(0.f);
    Qh[ob + 72 + z] = zero; Qh[ob + 84 + z] = zero;
    Kh[ob + 72 + z] = zero; Kh[ob + 84 + z] = zero;
    return;
  }
  const float c0 = cs[s * HD + d], s0 = sn[s * HD + d];
  const float c1 = cs[s * HD + d + 36], s1 = sn[s * HD + d + 36];
  const size_t qi = (size_t)s * QKV_N + h * HD;
  {
    const float x0 = __bfloat162float(Qkv[qi + d]);
    const float x1 = __bfloat162float(Qkv[qi + d + 36]);
    Qh[ob + d]      = __float2bfloat16((x0 * c0 - x1 * s0) * SCALE_QK);
    Qh[ob + d + 36] = __float2bfloat16((x1 * c1 + x0 * s1) * SCALE_QK);
  }
  {
    const float x0 = __bfloat162float(Qkv[qi + 1152 + d]);
    const float x1 = __bfloat162float(Qkv[qi + 1152 + d + 36]);
    Kh[ob + d]      = __float2bfloat16(x0 * c0 - x1 * s0);
    Kh[ob + d + 36] = __float2bfloat16(x1 * c1 + x0 * s1);
  }
}

// ---------------- flash attention: one (chunk,head,q-tile of 128) ---------
// 4 waves x 32 q-rows. Online softmax in registers. P redistribution via
// per-wave LDS plane [m=2][q=16][kv=128], granule XOR-swizzled by (q&7).
__global__ __launch_bounds__(256, 2)
void k_flash(const bf16* __restrict__ Qh, const bf16* __restrict__ Kh,
             const bf16* __restrict__ Vt, bf16* __restrict__ Jb) {
  __shared__ bf16 sK[128 * 96];    // 24 KB, [kv][96] swizzled c^=(kv&3)
  __shared__ bf16 sV[96 * 128];    // 24 KB, [d][128] swizzled c^=(d&7)
  __shared__ bf16 sP[4 * 4096];    // 32 KB: P planes (8KB/wave); doubles as sQ
  const int w = threadIdx.x >> 6, ln = threadIdx.x & 63;
  const int r = ln & 15, g = ln >> 4;
  const int h = blockIdx.y, s0 = blockIdx.z * CLEN;
  const int q0 = blockIdx.x * 128;
  const bf16* Qg = Qh + ((size_t)h * S_TOT + s0 + q0) * HDP;
  const bf16* Kg = Kh + ((size_t)h * S_TOT + s0) * HDP;
  const bf16* Vg = Vt + (size_t)h * HDP * S_TOT + s0;

  // Q tile -> sP region, then Q fragments to registers (once).
  stage128x96(Qg, sP, w, ln);
  __syncthreads();
  const char* sPb = (const char*)sP;
  bf16x8 qa[2][3];
#pragma unroll
  for (int m = 0; m < 2; ++m)
#pragma unroll
    for (int ks = 0; ks < 3; ++ks) {
      const int row = w * 32 + m * 16 + r;
      qa[m][ks] = *(const bf16x8*)(sPb + row * 192 + (((ks * 4 + g) ^ (row & 3)) << 4));
    }

  f32x4 oacc[2][6] = {};
  float mrun[2][4], lrun[2][4];
#pragma unroll
  for (int m = 0; m < 2; ++m)
#pragma unroll
    for (int j = 0; j < 4; ++j) { mrun[m][j] = -1e30f; lrun[m][j] = 0.f; }

  char* sPw = (char*)sP + w * 8192;
  const char* sKb = (const char*)sK;
  const char* sVb = (const char*)sV;

  for (int t = 0; t < 8; ++t) {
    __syncthreads();                       // prev tile consumed / qa loaded
    stage128x96(Kg + t * 128 * HDP, sK, w, ln);
    stageVt(Vg + t * 128, sV, w, ln);
    __syncthreads();                       // staging complete

    // ---- QK^T: acc[m][n][j] = S[q=w*32+m*16+g*4+j][kv=n*16+r] ----
    f32x4 acc[2][8] = {};
#pragma unroll
    for (int ks = 0; ks < 3; ++ks)
#pragma unroll
      for (int n = 0; n < 8; ++n) {
        const int kv = n * 16 + r;
        bf16x8 bv = *(const bf16x8*)(sKb + kv * 192 + (((ks * 4 + g) ^ (kv & 3)) << 4));
        acc[0][n] = __builtin_amdgcn_mfma_f32_16x16x32_bf16(qa[0][ks], bv, acc[0][n], 0, 0, 0);
        acc[1][n] = __builtin_amdgcn_mfma_f32_16x16x32_bf16(qa[1][ks], bv, acc[1][n], 0, 0, 0);
      }

    // ---- online softmax per row (m,j); 16 lanes of group g share rows ----
#pragma unroll
    for (int m = 0; m < 2; ++m)
#pragma unroll
      for (int j = 0; j < 4; ++j) {
        float tm = acc[m][0][j];
#pragma unroll
        for (int n = 1; n < 8; ++n) tm = fmaxf(tm, acc[m][n][j]);
#pragma unroll
        for (int o = 1; o < 16; o <<= 1) tm = fmaxf(tm, __shfl_xor(tm, o));
        const float mn = fmaxf(mrun[m][j], tm);
        const float esc = __expf(mrun[m][j] - mn);
        mrun[m][j] = mn;
        float sm = 0.f;
#pragma unroll
        for (int n = 0; n < 8; ++n) {
          const float p = __expf(acc[m][n][j] - mn);
          acc[m][n][j] = p; sm += p;
        }
#pragma unroll
        for (int o = 1; o < 16; o <<= 1) sm += __shfl_xor(sm, o);
        lrun[m][j] = lrun[m][j] * esc + sm;
#pragma unroll
        for (int n = 0; n < 6; ++n) oacc[m][n][j] *= esc;  // per-component
      }

    // ---- P -> per-wave plane [m][q=16][kv=128], granule ^= (q&7) ----
#pragma unroll
    for (int m = 0; m < 2; ++m)
#pragma unroll
      for (int n = 0; n < 8; ++n) {
        const int kv = n * 16 + r;
        const int gr = kv >> 3, wi = kv & 7;
#pragma unroll
        for (int j = 0; j < 4; ++j) {
          const int q = g * 4 + j;
          *(bf16*)(sPw + m * 4096 + q * 256 + ((gr ^ (q & 7)) << 4) + wi * 2) =
              __float2bfloat16(acc[m][n][j]);
        }
      }

    // ---- PV: O[q][d] += P[q][kv] V[kv][d]; A-frags = plane row r ----
#pragma unroll
    for (int ks = 0; ks < 4; ++ks) {
      bf16x8 pa[2];
#pragma unroll
      for (int m = 0; m < 2; ++m)
        pa[m] = *(const bf16x8*)(sPw + m * 4096 + r * 256 +
                                 (((ks * 4 + g) ^ (r & 7)) << 4));
#pragma unroll
      for (int n = 0; n < 6; ++n) {
        const int d = n * 16 + r;
        bf16x8 vb = *(const bf16x8*)(sVb + d * 256 + (((ks * 4 + g) ^ (d & 7)) << 4));
        oacc[0][n] = __builtin_amdgcn_mfma_f32_16x16x32_bf16(pa[0], vb, oacc[0][n], 0, 0, 0);
        oacc[1][n] = __builtin_amdgcn_mfma_f32_16x16x32_bf16(pa[1], vb, oacc[1][n], 0, 0, 0);
      }
    }
  }

  // ---- epilogue: O /= l, write Jb[s][h*72+d] for d<72 ----
#pragma unroll
  for (int m = 0; m < 2; ++m) {
    float inv[4];
#pragma unroll
    for (int j = 0; j < 4; ++j) inv[j] = 1.0f / lrun[m][j];
#pragma unroll
    for (int n = 0; n < 6; ++n) {
      const int d = n * 16 + r;
      if (d < HD) {
#pragma unroll
        for (int j = 0; j < 4; ++j) {
          const int row = s0 + q0 + w * 32 + m * 16 + g * 4 + j;
          Jb[(size_t)row * E_DIM + h * HD + d] = __float2bfloat16(oacc[m][n][j] * inv[j]);
        }
      }
    }
  }
}

// ---------------- out = attn @ proj_w^T + proj_b (plain bf16) -------------
__global__ __launch_bounds__(256, 2)
void k_proj(const bf16* __restrict__ Jb, const bf16* __restrict__ Pw,
            const float* __restrict__ bias, float* __restrict__ out) {
  __shared__ bf16 sA[128 * 32], sB[128 * 32];
  const int w = threadIdx.x >> 6, ln = threadIdx.x & 63;
  const int m0 = blockIdx.x * 128, n0 = blockIdx.y * 128;
  const bf16* A = Jb + (size_t)m0 * E_DIM;
  const bf16* B = Pw + (size_t)n0 * E_DIM;
  const int r = ln & 15, g = ln >> 4;
  const int wr = (w >> 1) * 64, wc = (w & 1) * 64;
  f32x4 acc[4][4] = {};
  for (int k0 = 0; k0 < E_DIM; k0 += 32) {
    __syncthreads();
    stage128x32(A + k0, E_DIM, sA, w, ln);
    stage128x32(B + k0, E_DIM, sB, w, ln);
    __syncthreads();
    bf16x8 a[4];
#pragma unroll
    for (int m = 0; m < 4; ++m)
      a[m] = *(const bf16x8*)&sA[(wr + m * 16 + r) * 32 + g * 8];
#pragma unroll
    for (int n = 0; n < 4; ++n) {
      bf16x8 bv = *(const bf16x8*)&sB[(wc + n * 16 + r) * 32 + g * 8];
#pragma unroll
      for (int m = 0; m < 4; ++m)
        acc[m][n] = __builtin_amdgcn_mfma_f32_16x16x32_bf16(a[m], bv, acc[m][n], 0, 0, 0);
    }
  }
#pragma unroll
  for (int n = 0; n < 4; ++n) {
    const int col = n0 + wc + n * 16 + r;
    const float bv = bias[col];
#pragma unroll
    for (int m = 0; m < 4; ++m)
#pragma unroll
      for (int j = 0; j < 4; ++j) {
        const int row = m0 + wr + m * 16 + g * 4 + j;
        out[(size_t)row * E_DIM + col] = acc[m][n][j] + bv;
      }
  }
}

// --------------------------------- launch ---------------------------------
extern "C" void kernel_launch(void* const* d_in, const int* in_sizes, int n_in,
                              void* d_out, int out_size, void* d_ws, size_t ws_size,
                              hipStream_t stream) {
  (void)in_sizes; (void)n_in; (void)out_size; (void)ws_size;
  const float* hs   = (const float*)d_in[0];
  const float* cosp = (const float*)d_in[1];
  const float* sinp = (const float*)d_in[2];
  const float* qkvw = (const float*)d_in[3];
  const float* qkvb = (const float*)d_in[4];
  const float* pw   = (const float*)d_in[5];
  const float* pb   = (const float*)d_in[6];
  float* out = (float*)d_out;
  char* ws = (char*)d_ws;

  bf16* Ab   = (bf16*)(ws + 0);          // hs bf16 [4096][1152]
  bf16* Wb   = (bf16*)(ws + 9437184);    // qkv_w bf16 [3456][1152]
  bf16* Pw   = (bf16*)(ws + 17399808);   // proj_w bf16 [1152][1152]
  bf16* Qkv  = (bf16*)(ws + 20054016);   // qkv out bf16 [4096][3456]
  bf16* Qh   = (bf16*)(ws + 48365568);   // q bf16 [16][4096][96], scaled
  bf16* Kh   = (bf16*)(ws + 60948480);   // k bf16 [16][4096][96]
  bf16* Vt   = (bf16*)(ws + 73531392);   // v^T bf16 [16][96][4096]
  bf16* Jb   = (bf16*)(ws + 86114304);   // attn bf16 [4096][1152]
  // total 95551488 bytes (~91 MiB)

  // Vt zero so pad rows d=72..95 are exact zeros
  hipMemsetAsync(ws + 73531392, 0, 12582912, stream);

  k_pack_plain<<<4608, 256, 0, stream>>>(hs, Ab);
  k_pack_plain<<<3888, 256, 0, stream>>>(qkvw, Wb);
  k_pack_plain<<<1296, 256, 0, stream>>>(pw, Pw);
  k_qkv_gemm<<<dim3(32, 27), 256, 0, stream>>>(Ab, Wb, qkvb, Qkv);
  k_vtrans<<<dim3(36, 128), dim3(32, 8), 0, stream>>>(Qkv, Vt);
  k_rope<<<12288, 256, 0, stream>>>(Qkv, cosp, sinp, Qh, Kh);
  k_flash<<<dim3(8, 16, 4), 256, 0, stream>>>(Qh, Kh, Vt, Jb);
  k_proj<<<dim3(32, 9), 256, 0, stream>>>(Jb, Pw, pb, out);
}

// Round 6
// 237.536 us; speedup vs baseline: 2.0375x; 1.0507x over previous
//
#include <hip/hip_runtime.h>
#include <hip/hip_bf16.h>

// Qwen3VL vision attention, MI355X. Round 6: flash kernel rework —
// (1) grid reorder so same-(head,chunk) q-tiles share an XCD L2 (8x K/V reuse),
// (2) counted-vmcnt staging split (K waited early, V hidden under QK+softmax),
// (3) swapped QK^T (mfma(K,Q)): softmax reduction lane-local (2 shfls), P-writes
//     16x ds_write_b64 instead of 64x b16; PV trimmed to d<80.

#define S_TOT 4096
#define E_DIM 1152
#define QKV_N 3456
#define NH    16
#define HD    72
#define HDP   96      // D padded to 96 for uniform K-steps of 32
#define CLEN  1024

static constexpr float SCALE_QK = 0.11785113019775793f;  // 72^-0.5

typedef __bf16 bf16x8 __attribute__((ext_vector_type(8)));
typedef float  f32x4  __attribute__((ext_vector_type(4)));
typedef unsigned int u32x2 __attribute__((ext_vector_type(2)));
typedef __hip_bfloat16 bf16;

// ---- async global->LDS, 16B per lane; LDS dest must be wave-uniform ----
__device__ __forceinline__ void gld_lds16(const void* g, void* l) {
  __builtin_amdgcn_global_load_lds(
      (const __attribute__((address_space(1))) unsigned int*)g,
      (__attribute__((address_space(3))) unsigned int*)l, 16, 0, 0);
}

// Stage a 128x32 bf16 tile (row-major, row stride ld elements) into LDS.
__device__ __forceinline__ void stage128x32(const bf16* src, int ld, bf16* dst,
                                            int w, int ln) {
#pragma unroll
  for (int c = 0; c < 2; ++c) {
    const int f = ((w * 2 + c) * 64 + ln) * 8;       // flat bf16 idx in tile
    gld_lds16(src + (f >> 5) * ld + (f & 31), dst + (w * 2 + c) * 512);
  }
}

// Stage a 128x96 CONTIGUOUS bf16 tile into LDS [128][96], granule swizzle
// c' = c ^ (row&3). Readers must apply the same XOR. 6 calls/lane.
__device__ __forceinline__ void stage128x96(const bf16* src, bf16* dst,
                                            int w, int ln) {
#pragma unroll
  for (int j = 0; j < 6; ++j) {
    const int f = (w * 6 + j) * 64 + ln;             // granule index [0,1536)
    const int row = f / 12, c = f % 12;
    gld_lds16(src + row * 96 + ((c ^ (row & 3)) << 3), dst + f * 8);
  }
}

// Stage rows d<80 of a 96x128 tile from Vt (row stride 4096) into LDS
// [96][128], granule swizzle c' = c ^ (d&7). 5 calls/lane.
__device__ __forceinline__ void stageVt5(const bf16* src, bf16* dst,
                                         int w, int ln) {
#pragma unroll
  for (int j = 0; j < 5; ++j) {
    const int f = (w * 5 + j) * 64 + ln;             // granule index [0,1280)
    const int d = f >> 4, c = f & 15;
    gld_lds16(src + (size_t)d * S_TOT + ((c ^ (d & 7)) << 3), dst + f * 8);
  }
}

__device__ __forceinline__ unsigned pack2(float a, float b) {
  const unsigned ua = __builtin_bit_cast(unsigned short, __float2bfloat16(a));
  const unsigned ub = __builtin_bit_cast(unsigned short, __float2bfloat16(b));
  return ua | (ub << 16);
}

// ---------------- pack fp32 -> bf16 ----------------
__global__ void k_pack_plain(const float* __restrict__ x, bf16* __restrict__ y) {
  const int i = blockIdx.x * blockDim.x + threadIdx.x;
  const float4 v = ((const float4*)x)[i];
  y[4 * i + 0] = __float2bfloat16(v.x);
  y[4 * i + 1] = __float2bfloat16(v.y);
  y[4 * i + 2] = __float2bfloat16(v.z);
  y[4 * i + 3] = __float2bfloat16(v.w);
}

// ---------------- QKV GEMM, plain bf16 -------------
__global__ __launch_bounds__(256, 2)
void k_qkv_gemm(const bf16* __restrict__ Ab, const bf16* __restrict__ Wb,
                const float* __restrict__ bias, bf16* __restrict__ C) {
  __shared__ bf16 sA[128 * 32], sB[128 * 32];
  const int w = threadIdx.x >> 6, ln = threadIdx.x & 63;
  const int m0 = blockIdx.x * 128, n0 = blockIdx.y * 128;
  const bf16* A = Ab + (size_t)m0 * E_DIM;
  const bf16* B = Wb + (size_t)n0 * E_DIM;
  const int r = ln & 15, g = ln >> 4;
  const int wr = (w >> 1) * 64, wc = (w & 1) * 64;
  f32x4 acc[4][4] = {};
  for (int k0 = 0; k0 < E_DIM; k0 += 32) {
    __syncthreads();
    stage128x32(A + k0, E_DIM, sA, w, ln);
    stage128x32(B + k0, E_DIM, sB, w, ln);
    __syncthreads();
    bf16x8 a[4];
#pragma unroll
    for (int m = 0; m < 4; ++m)
      a[m] = *(const bf16x8*)&sA[(wr + m * 16 + r) * 32 + g * 8];
#pragma unroll
    for (int n = 0; n < 4; ++n) {
      bf16x8 bv = *(const bf16x8*)&sB[(wc + n * 16 + r) * 32 + g * 8];
#pragma unroll
      for (int m = 0; m < 4; ++m)
        acc[m][n] = __builtin_amdgcn_mfma_f32_16x16x32_bf16(a[m], bv, acc[m][n], 0, 0, 0);
    }
  }
#pragma unroll
  for (int n = 0; n < 4; ++n) {
    const int col = n0 + wc + n * 16 + r;
    const float bv = bias[col];
#pragma unroll
    for (int m = 0; m < 4; ++m)
#pragma unroll
      for (int j = 0; j < 4; ++j) {
        const int row = m0 + wr + m * 16 + g * 4 + j;
        C[(size_t)row * QKV_N + col] = __float2bfloat16(acc[m][n][j] + bv);
      }
  }
}

// ---- V transpose: QKVb[s][2304 + h*72+d] -> Vt[h][d(96)][s] ----
__global__ void k_vtrans(const bf16* __restrict__ Qkv, bf16* __restrict__ Vt) {
  __shared__ bf16 t[32][33];
  const int hd0 = blockIdx.x * 32, s0 = blockIdx.y * 32;
  const int tx = threadIdx.x, ty = threadIdx.y;  // 32 x 8
#pragma unroll
  for (int k = 0; k < 4; ++k)
    t[ty + 8 * k][tx] = Qkv[(size_t)(s0 + ty + 8 * k) * QKV_N + 2304 + hd0 + tx];
  __syncthreads();
#pragma unroll
  for (int k = 0; k < 4; ++k) {
    const int hd = hd0 + ty + 8 * k;
    const int hh = hd / HD, dd = hd % HD;
    Vt[((size_t)hh * HDP + dd) * S_TOT + s0 + tx] = t[tx][ty + 8 * k];
  }
}

// ------- RoPE bf16 -> bf16 q,k in head-major [h][s][96]; q pre-scaled -----
__global__ void k_rope(const bf16* __restrict__ Qkv,
                       const float* __restrict__ cs, const float* __restrict__ sn,
                       bf16* __restrict__ Qh, bf16* __restrict__ Kh) {
  const int i = blockIdx.x * 256 + threadIdx.x;  // over 4096*16*48
  const int d = i % 48;
  const int h = (i / 48) & 15;
  const int s = i / (48 * 16);
  const size_t ob = ((size_t)h * S_TOT + s) * HDP;
  if (d >= 36) {
    const int z = d - 36;
    const bf16 zero = __float2bfloat16(0.f);
    Qh[ob + 72 + z] = zero; Qh[ob + 84 + z] = zero;
    Kh[ob + 72 + z] = zero; Kh[ob + 84 + z] = zero;
    return;
  }
  const float c0 = cs[s * HD + d], s0 = sn[s * HD + d];
  const float c1 = cs[s * HD + d + 36], s1 = sn[s * HD + d + 36];
  const size_t qi = (size_t)s * QKV_N + h * HD;
  {
    const float x0 = __bfloat162float(Qkv[qi + d]);
    const float x1 = __bfloat162float(Qkv[qi + d + 36]);
    Qh[ob + d]      = __float2bfloat16((x0 * c0 - x1 * s0) * SCALE_QK);
    Qh[ob + d + 36] = __float2bfloat16((x1 * c1 + x0 * s1) * SCALE_QK);
  }
  {
    const float x0 = __bfloat162float(Qkv[qi + 1152 + d]);
    const float x1 = __bfloat162float(Qkv[qi + 1152 + d + 36]);
    Kh[ob + d]      = __float2bfloat16(x0 * c0 - x1 * s0);
    Kh[ob + d + 36] = __float2bfloat16(x1 * c1 + x0 * s1);
  }
}

// ---------------- flash attention ----------------
// grid: x = h*4+chunk (fast -> XCD round-robin groups q-tiles per XCD),
//       y = q-tile. 4 waves x 32 q-rows.
// Swapped QK^T: acc[qb][kvb] holds P[kv=kvb*16+g*4+j][q=qb*16+r] -> softmax
// reduction is lane-local over 32 regs + 2 shfls; P written as b64 runs.
__global__ __launch_bounds__(256, 2)
void k_flash(const bf16* __restrict__ Qh, const bf16* __restrict__ Kh,
             const bf16* __restrict__ Vt, bf16* __restrict__ Jb) {
  __shared__ bf16 sK[128 * 96];    // [kv][96] swizzled c^=(kv&3)
  __shared__ bf16 sV[96 * 128];    // [d][128] swizzled c^=(d&7); rows d<80 used
  __shared__ bf16 sP[4 * 4096];    // P planes (8KB/wave); doubles as sQ
  const int w = threadIdx.x >> 6, ln = threadIdx.x & 63;
  const int r = ln & 15, g = ln >> 4;
  const int hc = blockIdx.x;
  const int h = hc >> 2, s0 = (hc & 3) * CLEN;
  const int q0 = blockIdx.y * 128;
  const bf16* Qg = Qh + ((size_t)h * S_TOT + s0 + q0) * HDP;
  const bf16* Kg = Kh + ((size_t)h * S_TOT + s0) * HDP;
  const bf16* Vg = Vt + (size_t)h * HDP * S_TOT + s0;

  // Q tile -> sP region, then Q B-fragments to registers (once).
  stage128x96(Qg, sP, w, ln);
  __syncthreads();
  const char* sPb = (const char*)sP;
  bf16x8 qa[2][3];
#pragma unroll
  for (int m = 0; m < 2; ++m)
#pragma unroll
    for (int ks = 0; ks < 3; ++ks) {
      const int row = w * 32 + m * 16 + r;
      qa[m][ks] = *(const bf16x8*)(sPb + row * 192 + (((ks * 4 + g) ^ (row & 3)) << 4));
    }

  f32x4 oacc[2][5] = {};
  float mrun[2] = {-1e30f, -1e30f}, lrun[2] = {0.f, 0.f};

  char* sPw = (char*)sP + w * 8192;
  const char* sKb = (const char*)sK;
  const char* sVb = (const char*)sV;
  const int ksw = r & 3;   // K row swizzle bits (kv*16 rows: row&3 == r&3)

  for (int t = 0; t < 8; ++t) {
    __syncthreads();                       // prev tile fully consumed
    stage128x96(Kg + t * 128 * HDP, sK, w, ln);   // 6 loads/lane
    stageVt5(Vg + t * 128, sV, w, ln);            // 5 loads/lane
    asm volatile("s_waitcnt vmcnt(5)" ::: "memory");  // K landed (own)
    __builtin_amdgcn_s_barrier();                     // all waves' K landed

    // ---- swapped QK^T: acc[qb][kvb][j] = S[kv=kvb*16+g*4+j][q=qb*16+r] ----
    f32x4 acc[2][8] = {};
#pragma unroll
    for (int kvb = 0; kvb < 8; ++kvb) {
      bf16x8 ka[3];
      const int row = kvb * 16 + r;
#pragma unroll
      for (int ks = 0; ks < 3; ++ks)
        ka[ks] = *(const bf16x8*)(sKb + row * 192 + (((ks * 4 + g) ^ ksw) << 4));
#pragma unroll
      for (int ks = 0; ks < 3; ++ks) {
        acc[0][kvb] = __builtin_amdgcn_mfma_f32_16x16x32_bf16(ka[ks], qa[0][ks], acc[0][kvb], 0, 0, 0);
        acc[1][kvb] = __builtin_amdgcn_mfma_f32_16x16x32_bf16(ka[ks], qa[1][ks], acc[1][kvb], 0, 0, 0);
      }
    }

    // ---- online softmax: q = qb*16 + r is lane-local ----
    float escr[2];
#pragma unroll
    for (int m = 0; m < 2; ++m) {
      float tm = acc[m][0][0];
#pragma unroll
      for (int kvb = 0; kvb < 8; ++kvb)
#pragma unroll
        for (int j = 0; j < 4; ++j) tm = fmaxf(tm, acc[m][kvb][j]);
      tm = fmaxf(tm, __shfl_xor(tm, 16));
      tm = fmaxf(tm, __shfl_xor(tm, 32));
      const float mn = fmaxf(mrun[m], tm);
      escr[m] = __expf(mrun[m] - mn);
      mrun[m] = mn;
      float sm = 0.f;
#pragma unroll
      for (int kvb = 0; kvb < 8; ++kvb)
#pragma unroll
        for (int j = 0; j < 4; ++j) {
          const float p = __expf(acc[m][kvb][j] - mn);
          acc[m][kvb][j] = p; sm += p;
        }
      sm += __shfl_xor(sm, 16);
      sm += __shfl_xor(sm, 32);
      lrun[m] = lrun[m] * escr[m] + sm;
    }
    // redistribute esc from q=r indexing to PV-output rows q=g*4+j
#pragma unroll
    for (int m = 0; m < 2; ++m)
#pragma unroll
      for (int j = 0; j < 4; ++j) {
        const float e = __shfl(escr[m], (ln & 48) | (g * 4 + j));
#pragma unroll
        for (int n = 0; n < 5; ++n) oacc[m][n][j] *= e;
      }

    // ---- P -> per-wave plane [qb][q=16][kv=128], b64 runs of 4 kv ----
#pragma unroll
    for (int m = 0; m < 2; ++m)
#pragma unroll
      for (int kvb = 0; kvb < 8; ++kvb) {
        u32x2 u;
        u.x = pack2(acc[m][kvb][0], acc[m][kvb][1]);
        u.y = pack2(acc[m][kvb][2], acc[m][kvb][3]);
        const int gsw = (kvb * 2 + (g >> 1)) ^ (r & 7);
        *(u32x2*)(sPw + m * 4096 + r * 256 + (gsw << 4) + (g & 1) * 8) = u;
      }

    asm volatile("s_waitcnt vmcnt(0)" ::: "memory");  // V landed (own)
    __builtin_amdgcn_s_barrier();                     // all waves' V landed

    // ---- PV: O[q][d] += P[q][kv] V[kv][d]; d<80 ----
#pragma unroll
    for (int ks = 0; ks < 4; ++ks) {
      bf16x8 pa[2];
#pragma unroll
      for (int m = 0; m < 2; ++m)
        pa[m] = *(const bf16x8*)(sPw + m * 4096 + r * 256 +
                                 (((ks * 4 + g) ^ (r & 7)) << 4));
#pragma unroll
      for (int n = 0; n < 5; ++n) {
        const int d = n * 16 + r;
        bf16x8 vb = *(const bf16x8*)(sVb + d * 256 + (((ks * 4 + g) ^ (d & 7)) << 4));
        oacc[0][n] = __builtin_amdgcn_mfma_f32_16x16x32_bf16(pa[0], vb, oacc[0][n], 0, 0, 0);
        oacc[1][n] = __builtin_amdgcn_mfma_f32_16x16x32_bf16(pa[1], vb, oacc[1][n], 0, 0, 0);
      }
    }
  }

  // ---- epilogue: O /= l (redistributed), write Jb for d<72 ----
#pragma unroll
  for (int m = 0; m < 2; ++m) {
    float inv[4];
#pragma unroll
    for (int j = 0; j < 4; ++j)
      inv[j] = 1.0f / __shfl(lrun[m], (ln & 48) | (g * 4 + j));
#pragma unroll
    for (int n = 0; n < 5; ++n) {
      const int d = n * 16 + r;
      if (d < HD) {
#pragma unroll
        for (int j = 0; j < 4; ++j) {
          const int row = s0 + q0 + w * 32 + m * 16 + g * 4 + j;
          Jb[(size_t)row * E_DIM + h * HD + d] = __float2bfloat16(oacc[m][n][j] * inv[j]);
        }
      }
    }
  }
}

// ---------------- out = attn @ proj_w^T + proj_b (plain bf16) -------------
__global__ __launch_bounds__(256, 2)
void k_proj(const bf16* __restrict__ Jb, const bf16* __restrict__ Pw,
            const float* __restrict__ bias, float* __restrict__ out) {
  __shared__ bf16 sA[128 * 32], sB[128 * 32];
  const int w = threadIdx.x >> 6, ln = threadIdx.x & 63;
  const int m0 = blockIdx.x * 128, n0 = blockIdx.y * 128;
  const bf16* A = Jb + (size_t)m0 * E_DIM;
  const bf16* B = Pw + (size_t)n0 * E_DIM;
  const int r = ln & 15, g = ln >> 4;
  const int wr = (w >> 1) * 64, wc = (w & 1) * 64;
  f32x4 acc[4][4] = {};
  for (int k0 = 0; k0 < E_DIM; k0 += 32) {
    __syncthreads();
    stage128x32(A + k0, E_DIM, sA, w, ln);
    stage128x32(B + k0, E_DIM, sB, w, ln);
    __syncthreads();
    bf16x8 a[4];
#pragma unroll
    for (int m = 0; m < 4; ++m)
      a[m] = *(const bf16x8*)&sA[(wr + m * 16 + r) * 32 + g * 8];
#pragma unroll
    for (int n = 0; n < 4; ++n) {
      bf16x8 bv = *(const bf16x8*)&sB[(wc + n * 16 + r) * 32 + g * 8];
#pragma unroll
      for (int m = 0; m < 4; ++m)
        acc[m][n] = __builtin_amdgcn_mfma_f32_16x16x32_bf16(a[m], bv, acc[m][n], 0, 0, 0);
    }
  }
#pragma unroll
  for (int n = 0; n < 4; ++n) {
    const int col = n0 + wc + n * 16 + r;
    const float bv = bias[col];
#pragma unroll
    for (int m = 0; m < 4; ++m)
#pragma unroll
      for (int j = 0; j < 4; ++j) {
        const int row = m0 + wr + m * 16 + g * 4 + j;
        out[(size_t)row * E_DIM + col] = acc[m][n][j] + bv;
      }
  }
}

// --------------------------------- launch ---------------------------------
extern "C" void kernel_launch(void* const* d_in, const int* in_sizes, int n_in,
                              void* d_out, int out_size, void* d_ws, size_t ws_size,
                              hipStream_t stream) {
  (void)in_sizes; (void)n_in; (void)out_size; (void)ws_size;
  const float* hs   = (const float*)d_in[0];
  const float* cosp = (const float*)d_in[1];
  const float* sinp = (const float*)d_in[2];
  const float* qkvw = (const float*)d_in[3];
  const float* qkvb = (const float*)d_in[4];
  const float* pw   = (const float*)d_in[5];
  const float* pb   = (const float*)d_in[6];
  float* out = (float*)d_out;
  char* ws = (char*)d_ws;

  bf16* Ab   = (bf16*)(ws + 0);          // hs bf16 [4096][1152]
  bf16* Wb   = (bf16*)(ws + 9437184);    // qkv_w bf16 [3456][1152]
  bf16* Pw   = (bf16*)(ws + 17399808);   // proj_w bf16 [1152][1152]
  bf16* Qkv  = (bf16*)(ws + 20054016);   // qkv out bf16 [4096][3456]
  bf16* Qh   = (bf16*)(ws + 48365568);   // q bf16 [16][4096][96], scaled
  bf16* Kh   = (bf16*)(ws + 60948480);   // k bf16 [16][4096][96]
  bf16* Vt   = (bf16*)(ws + 73531392);   // v^T bf16 [16][96][4096]
  bf16* Jb   = (bf16*)(ws + 86114304);   // attn bf16 [4096][1152]
  // total 95551488 bytes (~91 MiB)

  // Vt zero so pad rows d=72..95 are exact zeros
  hipMemsetAsync(ws + 73531392, 0, 12582912, stream);

  k_pack_plain<<<4608, 256, 0, stream>>>(hs, Ab);
  k_pack_plain<<<3888, 256, 0, stream>>>(qkvw, Wb);
  k_pack_plain<<<1296, 256, 0, stream>>>(pw, Pw);
  k_qkv_gemm<<<dim3(32, 27), 256, 0, stream>>>(Ab, Wb, qkvb, Qkv);
  k_vtrans<<<dim3(36, 128), dim3(32, 8), 0, stream>>>(Qkv, Vt);
  k_rope<<<12288, 256, 0, stream>>>(Qkv, cosp, sinp, Qh, Kh);
  k_flash<<<dim3(64, 8), 256, 0, stream>>>(Qh, Kh, Vt, Jb);
  k_proj<<<dim3(32, 9), 256, 0, stream>>>(Jb, Pw, pb, out);
}

// Round 7
// 227.744 us; speedup vs baseline: 2.1251x; 1.0430x over previous
//
#include <hip/hip_runtime.h>
#include <hip/hip_bf16.h>

// Qwen3VL vision attention, MI355X. Round 7:
// (1) k_qkv_gemm / k_proj: 2-phase double-buffered LDS (prefetch next K-tile
//     into buf^1 before computing buf; ONE barrier per K-step) — removes the
//     per-iter exposed vmcnt(0) HBM drain of the 1-phase structure.
// (2) three pack kernels fused into one (contiguous dst regions).
// Flash kernel unchanged from R6 (grid-XCD grouping + swapped QK^T + counted
// vmcnt staging).

#define S_TOT 4096
#define E_DIM 1152
#define QKV_N 3456
#define NH    16
#define HD    72
#define HDP   96      // D padded to 96 for uniform K-steps of 32
#define CLEN  1024

static constexpr float SCALE_QK = 0.11785113019775793f;  // 72^-0.5

typedef __bf16 bf16x8 __attribute__((ext_vector_type(8)));
typedef float  f32x4  __attribute__((ext_vector_type(4)));
typedef unsigned int u32x2 __attribute__((ext_vector_type(2)));
typedef __hip_bfloat16 bf16;

// ---- async global->LDS, 16B per lane; LDS dest must be wave-uniform ----
__device__ __forceinline__ void gld_lds16(const void* g, void* l) {
  __builtin_amdgcn_global_load_lds(
      (const __attribute__((address_space(1))) unsigned int*)g,
      (__attribute__((address_space(3))) unsigned int*)l, 16, 0, 0);
}

// Stage a 128x32 bf16 tile (row-major, row stride ld elements) into LDS.
__device__ __forceinline__ void stage128x32(const bf16* src, int ld, bf16* dst,
                                            int w, int ln) {
#pragma unroll
  for (int c = 0; c < 2; ++c) {
    const int f = ((w * 2 + c) * 64 + ln) * 8;       // flat bf16 idx in tile
    gld_lds16(src + (f >> 5) * ld + (f & 31), dst + (w * 2 + c) * 512);
  }
}

// Stage a 128x96 CONTIGUOUS bf16 tile into LDS [128][96], granule swizzle
// c' = c ^ (row&3). Readers must apply the same XOR. 6 calls/lane.
__device__ __forceinline__ void stage128x96(const bf16* src, bf16* dst,
                                            int w, int ln) {
#pragma unroll
  for (int j = 0; j < 6; ++j) {
    const int f = (w * 6 + j) * 64 + ln;             // granule index [0,1536)
    const int row = f / 12, c = f % 12;
    gld_lds16(src + row * 96 + ((c ^ (row & 3)) << 3), dst + f * 8);
  }
}

// Stage rows d<80 of a 96x128 tile from Vt (row stride 4096) into LDS
// [96][128], granule swizzle c' = c ^ (d&7). 5 calls/lane.
__device__ __forceinline__ void stageVt5(const bf16* src, bf16* dst,
                                         int w, int ln) {
#pragma unroll
  for (int j = 0; j < 5; ++j) {
    const int f = (w * 5 + j) * 64 + ln;             // granule index [0,1280)
    const int d = f >> 4, c = f & 15;
    gld_lds16(src + (size_t)d * S_TOT + ((c ^ (d & 7)) << 3), dst + f * 8);
  }
}

__device__ __forceinline__ unsigned pack2(float a, float b) {
  const unsigned ua = __builtin_bit_cast(unsigned short, __float2bfloat16(a));
  const unsigned ub = __builtin_bit_cast(unsigned short, __float2bfloat16(b));
  return ua | (ub << 16);
}

// ------- fused pack fp32 -> bf16 for hs | qkv_w | proj_w (contiguous dst) ---
// region boundaries are multiples of 256 float4s -> branch is block-uniform.
__global__ void k_pack_all(const float* __restrict__ a, const float* __restrict__ b,
                           const float* __restrict__ c, bf16* __restrict__ dst) {
  const int i = blockIdx.x * 256 + threadIdx.x;   // float4 index, [0, 2506752)
  const float* src; int base;
  if (i < 1179648)      { src = a; base = 0; }
  else if (i < 2174976) { src = b; base = 1179648; }
  else                  { src = c; base = 2174976; }
  const float4 v = ((const float4*)src)[i - base];
  dst[4 * i + 0] = __float2bfloat16(v.x);
  dst[4 * i + 1] = __float2bfloat16(v.y);
  dst[4 * i + 2] = __float2bfloat16(v.z);
  dst[4 * i + 3] = __float2bfloat16(v.w);
}

// ---------------- QKV GEMM, plain bf16, 2-phase double-buffered -----------
__global__ __launch_bounds__(256, 2)
void k_qkv_gemm(const bf16* __restrict__ Ab, const bf16* __restrict__ Wb,
                const float* __restrict__ bias, bf16* __restrict__ C) {
  __shared__ bf16 sA[2][128 * 32], sB[2][128 * 32];
  const int w = threadIdx.x >> 6, ln = threadIdx.x & 63;
  const int m0 = blockIdx.x * 128, n0 = blockIdx.y * 128;
  const bf16* A = Ab + (size_t)m0 * E_DIM;
  const bf16* B = Wb + (size_t)n0 * E_DIM;
  const int r = ln & 15, g = ln >> 4;
  const int wr = (w >> 1) * 64, wc = (w & 1) * 64;
  f32x4 acc[4][4] = {};

  auto compute = [&](int cur) {
    bf16x8 a[4];
#pragma unroll
    for (int m = 0; m < 4; ++m)
      a[m] = *(const bf16x8*)&sA[cur][(wr + m * 16 + r) * 32 + g * 8];
#pragma unroll
    for (int n = 0; n < 4; ++n) {
      bf16x8 bv = *(const bf16x8*)&sB[cur][(wc + n * 16 + r) * 32 + g * 8];
#pragma unroll
      for (int m = 0; m < 4; ++m)
        acc[m][n] = __builtin_amdgcn_mfma_f32_16x16x32_bf16(a[m], bv, acc[m][n], 0, 0, 0);
    }
  };

  stage128x32(A, E_DIM, sA[0], w, ln);
  stage128x32(B, E_DIM, sB[0], w, ln);
  __syncthreads();                       // implicit vmcnt(0) drain
  int cur = 0;
  for (int k0 = 32; k0 < E_DIM; k0 += 32) {
    stage128x32(A + k0, E_DIM, sA[cur ^ 1], w, ln);   // prefetch next
    stage128x32(B + k0, E_DIM, sB[cur ^ 1], w, ln);
    compute(cur);                        // overlap with loads in flight
    __syncthreads();                     // drain prefetch + all waves done
    cur ^= 1;
  }
  compute(cur);

#pragma unroll
  for (int n = 0; n < 4; ++n) {
    const int col = n0 + wc + n * 16 + r;
    const float bv = bias[col];
#pragma unroll
    for (int m = 0; m < 4; ++m)
#pragma unroll
      for (int j = 0; j < 4; ++j) {
        const int row = m0 + wr + m * 16 + g * 4 + j;
        C[(size_t)row * QKV_N + col] = __float2bfloat16(acc[m][n][j] + bv);
      }
  }
}

// ---- V transpose: QKVb[s][2304 + h*72+d] -> Vt[h][d(96)][s] ----
__global__ void k_vtrans(const bf16* __restrict__ Qkv, bf16* __restrict__ Vt) {
  __shared__ bf16 t[32][33];
  const int hd0 = blockIdx.x * 32, s0 = blockIdx.y * 32;
  const int tx = threadIdx.x, ty = threadIdx.y;  // 32 x 8
#pragma unroll
  for (int k = 0; k < 4; ++k)
    t[ty + 8 * k][tx] = Qkv[(size_t)(s0 + ty + 8 * k) * QKV_N + 2304 + hd0 + tx];
  __syncthreads();
#pragma unroll
  for (int k = 0; k < 4; ++k) {
    const int hd = hd0 + ty + 8 * k;
    const int hh = hd / HD, dd = hd % HD;
    Vt[((size_t)hh * HDP + dd) * S_TOT + s0 + tx] = t[tx][ty + 8 * k];
  }
}

// ------- RoPE bf16 -> bf16 q,k in head-major [h][s][96]; q pre-scaled -----
__global__ void k_rope(const bf16* __restrict__ Qkv,
                       const float* __restrict__ cs, const float* __restrict__ sn,
                       bf16* __restrict__ Qh, bf16* __restrict__ Kh) {
  const int i = blockIdx.x * 256 + threadIdx.x;  // over 4096*16*48
  const int d = i % 48;
  const int h = (i / 48) & 15;
  const int s = i / (48 * 16);
  const size_t ob = ((size_t)h * S_TOT + s) * HDP;
  if (d >= 36) {
    const int z = d - 36;
    const bf16 zero = __float2bfloat16(0.f);
    Qh[ob + 72 + z] = zero; Qh[ob + 84 + z] = zero;
    Kh[ob + 72 + z] = zero; Kh[ob + 84 + z] = zero;
    return;
  }
  const float c0 = cs[s * HD + d], s0 = sn[s * HD + d];
  const float c1 = cs[s * HD + d + 36], s1 = sn[s * HD + d + 36];
  const size_t qi = (size_t)s * QKV_N + h * HD;
  {
    const float x0 = __bfloat162float(Qkv[qi + d]);
    const float x1 = __bfloat162float(Qkv[qi + d + 36]);
    Qh[ob + d]      = __float2bfloat16((x0 * c0 - x1 * s0) * SCALE_QK);
    Qh[ob + d + 36] = __float2bfloat16((x1 * c1 + x0 * s1) * SCALE_QK);
  }
  {
    const float x0 = __bfloat162float(Qkv[qi + 1152 + d]);
    const float x1 = __bfloat162float(Qkv[qi + 1152 + d + 36]);
    Kh[ob + d]      = __float2bfloat16(x0 * c0 - x1 * s0);
    Kh[ob + d + 36] = __float2bfloat16(x1 * c1 + x0 * s1);
  }
}

// ---------------- flash attention (unchanged from R6) ----------------
__global__ __launch_bounds__(256, 2)
void k_flash(const bf16* __restrict__ Qh, const bf16* __restrict__ Kh,
             const bf16* __restrict__ Vt, bf16* __restrict__ Jb) {
  __shared__ bf16 sK[128 * 96];    // [kv][96] swizzled c^=(kv&3)
  __shared__ bf16 sV[96 * 128];    // [d][128] swizzled c^=(d&7); rows d<80 used
  __shared__ bf16 sP[4 * 4096];    // P planes (8KB/wave); doubles as sQ
  const int w = threadIdx.x >> 6, ln = threadIdx.x & 63;
  const int r = ln & 15, g = ln >> 4;
  const int hc = blockIdx.x;
  const int h = hc >> 2, s0 = (hc & 3) * CLEN;
  const int q0 = blockIdx.y * 128;
  const bf16* Qg = Qh + ((size_t)h * S_TOT + s0 + q0) * HDP;
  const bf16* Kg = Kh + ((size_t)h * S_TOT + s0) * HDP;
  const bf16* Vg = Vt + (size_t)h * HDP * S_TOT + s0;

  stage128x96(Qg, sP, w, ln);
  __syncthreads();
  const char* sPb = (const char*)sP;
  bf16x8 qa[2][3];
#pragma unroll
  for (int m = 0; m < 2; ++m)
#pragma unroll
    for (int ks = 0; ks < 3; ++ks) {
      const int row = w * 32 + m * 16 + r;
      qa[m][ks] = *(const bf16x8*)(sPb + row * 192 + (((ks * 4 + g) ^ (row & 3)) << 4));
    }

  f32x4 oacc[2][5] = {};
  float mrun[2] = {-1e30f, -1e30f}, lrun[2] = {0.f, 0.f};

  char* sPw = (char*)sP + w * 8192;
  const char* sKb = (const char*)sK;
  const char* sVb = (const char*)sV;
  const int ksw = r & 3;

  for (int t = 0; t < 8; ++t) {
    __syncthreads();
    stage128x96(Kg + t * 128 * HDP, sK, w, ln);   // 6 loads/lane
    stageVt5(Vg + t * 128, sV, w, ln);            // 5 loads/lane
    asm volatile("s_waitcnt vmcnt(5)" ::: "memory");  // K landed (own)
    __builtin_amdgcn_s_barrier();                     // all waves' K landed

    f32x4 acc[2][8] = {};
#pragma unroll
    for (int kvb = 0; kvb < 8; ++kvb) {
      bf16x8 ka[3];
      const int row = kvb * 16 + r;
#pragma unroll
      for (int ks = 0; ks < 3; ++ks)
        ka[ks] = *(const bf16x8*)(sKb + row * 192 + (((ks * 4 + g) ^ ksw) << 4));
#pragma unroll
      for (int ks = 0; ks < 3; ++ks) {
        acc[0][kvb] = __builtin_amdgcn_mfma_f32_16x16x32_bf16(ka[ks], qa[0][ks], acc[0][kvb], 0, 0, 0);
        acc[1][kvb] = __builtin_amdgcn_mfma_f32_16x16x32_bf16(ka[ks], qa[1][ks], acc[1][kvb], 0, 0, 0);
      }
    }

    float escr[2];
#pragma unroll
    for (int m = 0; m < 2; ++m) {
      float tm = acc[m][0][0];
#pragma unroll
      for (int kvb = 0; kvb < 8; ++kvb)
#pragma unroll
        for (int j = 0; j < 4; ++j) tm = fmaxf(tm, acc[m][kvb][j]);
      tm = fmaxf(tm, __shfl_xor(tm, 16));
      tm = fmaxf(tm, __shfl_xor(tm, 32));
      const float mn = fmaxf(mrun[m], tm);
      escr[m] = __expf(mrun[m] - mn);
      mrun[m] = mn;
      float sm = 0.f;
#pragma unroll
      for (int kvb = 0; kvb < 8; ++kvb)
#pragma unroll
        for (int j = 0; j < 4; ++j) {
          const float p = __expf(acc[m][kvb][j] - mn);
          acc[m][kvb][j] = p; sm += p;
        }
      sm += __shfl_xor(sm, 16);
      sm += __shfl_xor(sm, 32);
      lrun[m] = lrun[m] * escr[m] + sm;
    }
#pragma unroll
    for (int m = 0; m < 2; ++m)
#pragma unroll
      for (int j = 0; j < 4; ++j) {
        const float e = __shfl(escr[m], (ln & 48) | (g * 4 + j));
#pragma unroll
        for (int n = 0; n < 5; ++n) oacc[m][n][j] *= e;
      }

#pragma unroll
    for (int m = 0; m < 2; ++m)
#pragma unroll
      for (int kvb = 0; kvb < 8; ++kvb) {
        u32x2 u;
        u.x = pack2(acc[m][kvb][0], acc[m][kvb][1]);
        u.y = pack2(acc[m][kvb][2], acc[m][kvb][3]);
        const int gsw = (kvb * 2 + (g >> 1)) ^ (r & 7);
        *(u32x2*)(sPw + m * 4096 + r * 256 + (gsw << 4) + (g & 1) * 8) = u;
      }

    asm volatile("s_waitcnt vmcnt(0)" ::: "memory");  // V landed (own)
    __builtin_amdgcn_s_barrier();                     // all waves' V landed

#pragma unroll
    for (int ks = 0; ks < 4; ++ks) {
      bf16x8 pa[2];
#pragma unroll
      for (int m = 0; m < 2; ++m)
        pa[m] = *(const bf16x8*)(sPw + m * 4096 + r * 256 +
                                 (((ks * 4 + g) ^ (r & 7)) << 4));
#pragma unroll
      for (int n = 0; n < 5; ++n) {
        const int d = n * 16 + r;
        bf16x8 vb = *(const bf16x8*)(sVb + d * 256 + (((ks * 4 + g) ^ (d & 7)) << 4));
        oacc[0][n] = __builtin_amdgcn_mfma_f32_16x16x32_bf16(pa[0], vb, oacc[0][n], 0, 0, 0);
        oacc[1][n] = __builtin_amdgcn_mfma_f32_16x16x32_bf16(pa[1], vb, oacc[1][n], 0, 0, 0);
      }
    }
  }

#pragma unroll
  for (int m = 0; m < 2; ++m) {
    float inv[4];
#pragma unroll
    for (int j = 0; j < 4; ++j)
      inv[j] = 1.0f / __shfl(lrun[m], (ln & 48) | (g * 4 + j));
#pragma unroll
    for (int n = 0; n < 5; ++n) {
      const int d = n * 16 + r;
      if (d < HD) {
#pragma unroll
        for (int j = 0; j < 4; ++j) {
          const int row = s0 + q0 + w * 32 + m * 16 + g * 4 + j;
          Jb[(size_t)row * E_DIM + h * HD + d] = __float2bfloat16(oacc[m][n][j] * inv[j]);
        }
      }
    }
  }
}

// ------- out = attn @ proj_w^T + proj_b, 2-phase double-buffered ----------
__global__ __launch_bounds__(256, 2)
void k_proj(const bf16* __restrict__ Jb, const bf16* __restrict__ Pw,
            const float* __restrict__ bias, float* __restrict__ out) {
  __shared__ bf16 sA[2][128 * 32], sB[2][128 * 32];
  const int w = threadIdx.x >> 6, ln = threadIdx.x & 63;
  const int m0 = blockIdx.x * 128, n0 = blockIdx.y * 128;
  const bf16* A = Jb + (size_t)m0 * E_DIM;
  const bf16* B = Pw + (size_t)n0 * E_DIM;
  const int r = ln & 15, g = ln >> 4;
  const int wr = (w >> 1) * 64, wc = (w & 1) * 64;
  f32x4 acc[4][4] = {};

  auto compute = [&](int cur) {
    bf16x8 a[4];
#pragma unroll
    for (int m = 0; m < 4; ++m)
      a[m] = *(const bf16x8*)&sA[cur][(wr + m * 16 + r) * 32 + g * 8];
#pragma unroll
    for (int n = 0; n < 4; ++n) {
      bf16x8 bv = *(const bf16x8*)&sB[cur][(wc + n * 16 + r) * 32 + g * 8];
#pragma unroll
      for (int m = 0; m < 4; ++m)
        acc[m][n] = __builtin_amdgcn_mfma_f32_16x16x32_bf16(a[m], bv, acc[m][n], 0, 0, 0);
    }
  };

  stage128x32(A, E_DIM, sA[0], w, ln);
  stage128x32(B, E_DIM, sB[0], w, ln);
  __syncthreads();
  int cur = 0;
  for (int k0 = 32; k0 < E_DIM; k0 += 32) {
    stage128x32(A + k0, E_DIM, sA[cur ^ 1], w, ln);
    stage128x32(B + k0, E_DIM, sB[cur ^ 1], w, ln);
    compute(cur);
    __syncthreads();
    cur ^= 1;
  }
  compute(cur);

#pragma unroll
  for (int n = 0; n < 4; ++n) {
    const int col = n0 + wc + n * 16 + r;
    const float bv = bias[col];
#pragma unroll
    for (int m = 0; m < 4; ++m)
#pragma unroll
      for (int j = 0; j < 4; ++j) {
        const int row = m0 + wr + m * 16 + g * 4 + j;
        out[(size_t)row * E_DIM + col] = acc[m][n][j] + bv;
      }
  }
}

// --------------------------------- launch ---------------------------------
extern "C" void kernel_launch(void* const* d_in, const int* in_sizes, int n_in,
                              void* d_out, int out_size, void* d_ws, size_t ws_size,
                              hipStream_t stream) {
  (void)in_sizes; (void)n_in; (void)out_size; (void)ws_size;
  const float* hs   = (const float*)d_in[0];
  const float* cosp = (const float*)d_in[1];
  const float* sinp = (const float*)d_in[2];
  const float* qkvw = (const float*)d_in[3];
  const float* qkvb = (const float*)d_in[4];
  const float* pw   = (const float*)d_in[5];
  const float* pb   = (const float*)d_in[6];
  float* out = (float*)d_out;
  char* ws = (char*)d_ws;

  bf16* Ab   = (bf16*)(ws + 0);          // hs bf16 [4096][1152]
  bf16* Wb   = (bf16*)(ws + 9437184);    // qkv_w bf16 [3456][1152]
  bf16* Pw   = (bf16*)(ws + 17399808);   // proj_w bf16 [1152][1152]
  bf16* Qkv  = (bf16*)(ws + 20054016);   // qkv out bf16 [4096][3456]
  bf16* Qh   = (bf16*)(ws + 48365568);   // q bf16 [16][4096][96], scaled
  bf16* Kh   = (bf16*)(ws + 60948480);   // k bf16 [16][4096][96]
  bf16* Vt   = (bf16*)(ws + 73531392);   // v^T bf16 [16][96][4096]
  bf16* Jb   = (bf16*)(ws + 86114304);   // attn bf16 [4096][1152]
  // total 95551488 bytes (~91 MiB)

  // Vt zero so pad rows d=72..95 are exact zeros
  hipMemsetAsync(ws + 73531392, 0, 12582912, stream);

  k_pack_all<<<9792, 256, 0, stream>>>(hs, qkvw, pw, Ab);
  k_qkv_gemm<<<dim3(32, 27), 256, 0, stream>>>(Ab, Wb, qkvb, Qkv);
  k_vtrans<<<dim3(36, 128), dim3(32, 8), 0, stream>>>(Qkv, Vt);
  k_rope<<<12288, 256, 0, stream>>>(Qkv, cosp, sinp, Qh, Kh);
  k_flash<<<dim3(64, 8), 256, 0, stream>>>(Qh, Kh, Vt, Jb);
  k_proj<<<dim3(32, 9), 256, 0, stream>>>(Jb, Pw, pb, out);
}

// Round 8
// 222.612 us; speedup vs baseline: 2.1741x; 1.0231x over previous
//
#include <hip/hip_runtime.h>
#include <hip/hip_bf16.h>

// Qwen3VL vision attention, MI355X. Round 8: vectorize the glue.
// (1) k_rope: quad-vectorized (8B u32x2 loads/stores, float4 cos/sin),
//     pad zeros folded in. Was 2B-scalar (~8x off coalescing ideal).
// (2) k_vtrans: 64x64 tile, 16B loads, LDS transpose ([64][76] pad),
//     16B stores; Vt pad rows d=72..79 zero-filled here -> memset dropped.
// GEMMs + flash unchanged from R7 (2-phase dbuf 128^2; flash swapped-QK).

#define S_TOT 4096
#define E_DIM 1152
#define QKV_N 3456
#define NH    16
#define HD    72
#define HDP   96
#define CLEN  1024

static constexpr float SCALE_QK = 0.11785113019775793f;  // 72^-0.5

typedef __bf16 bf16x8 __attribute__((ext_vector_type(8)));
typedef float  f32x4  __attribute__((ext_vector_type(4)));
typedef unsigned int u32x2 __attribute__((ext_vector_type(2)));
typedef unsigned int u32x4 __attribute__((ext_vector_type(4)));
typedef __hip_bfloat16 bf16;

// ---- async global->LDS, 16B per lane; LDS dest must be wave-uniform ----
__device__ __forceinline__ void gld_lds16(const void* g, void* l) {
  __builtin_amdgcn_global_load_lds(
      (const __attribute__((address_space(1))) unsigned int*)g,
      (__attribute__((address_space(3))) unsigned int*)l, 16, 0, 0);
}

__device__ __forceinline__ void stage128x32(const bf16* src, int ld, bf16* dst,
                                            int w, int ln) {
#pragma unroll
  for (int c = 0; c < 2; ++c) {
    const int f = ((w * 2 + c) * 64 + ln) * 8;
    gld_lds16(src + (f >> 5) * ld + (f & 31), dst + (w * 2 + c) * 512);
  }
}

__device__ __forceinline__ void stage128x96(const bf16* src, bf16* dst,
                                            int w, int ln) {
#pragma unroll
  for (int j = 0; j < 6; ++j) {
    const int f = (w * 6 + j) * 64 + ln;
    const int row = f / 12, c = f % 12;
    gld_lds16(src + row * 96 + ((c ^ (row & 3)) << 3), dst + f * 8);
  }
}

__device__ __forceinline__ void stageVt5(const bf16* src, bf16* dst,
                                         int w, int ln) {
#pragma unroll
  for (int j = 0; j < 5; ++j) {
    const int f = (w * 5 + j) * 64 + ln;
    const int d = f >> 4, c = f & 15;
    gld_lds16(src + (size_t)d * S_TOT + ((c ^ (d & 7)) << 3), dst + f * 8);
  }
}

__device__ __forceinline__ unsigned pack2(float a, float b) {
  const unsigned ua = __builtin_bit_cast(unsigned short, __float2bfloat16(a));
  const unsigned ub = __builtin_bit_cast(unsigned short, __float2bfloat16(b));
  return ua | (ub << 16);
}
__device__ __forceinline__ float bl16(unsigned u) {  // low bf16 -> f32 (exact)
  return __uint_as_float(u << 16);
}
__device__ __forceinline__ float bh16(unsigned u) {  // high bf16 -> f32
  return __uint_as_float(u & 0xffff0000u);
}

// ------- fused pack fp32 -> bf16 for hs | qkv_w | proj_w (contiguous dst) ---
__global__ void k_pack_all(const float* __restrict__ a, const float* __restrict__ b,
                           const float* __restrict__ c, bf16* __restrict__ dst) {
  const int i = blockIdx.x * 256 + threadIdx.x;   // float4 index, [0, 2506752)
  const float* src; int base;
  if (i < 1179648)      { src = a; base = 0; }
  else if (i < 2174976) { src = b; base = 1179648; }
  else                  { src = c; base = 2174976; }
  const float4 v = ((const float4*)src)[i - base];
  u32x2 o;
  o.x = pack2(v.x, v.y);
  o.y = pack2(v.z, v.w);
  *(u32x2*)(dst + 4 * (size_t)i) = o;
}

// ---------------- QKV GEMM, plain bf16, 2-phase double-buffered -----------
__global__ __launch_bounds__(256, 2)
void k_qkv_gemm(const bf16* __restrict__ Ab, const bf16* __restrict__ Wb,
                const float* __restrict__ bias, bf16* __restrict__ C) {
  __shared__ bf16 sA[2][128 * 32], sB[2][128 * 32];
  const int w = threadIdx.x >> 6, ln = threadIdx.x & 63;
  const int m0 = blockIdx.x * 128, n0 = blockIdx.y * 128;
  const bf16* A = Ab + (size_t)m0 * E_DIM;
  const bf16* B = Wb + (size_t)n0 * E_DIM;
  const int r = ln & 15, g = ln >> 4;
  const int wr = (w >> 1) * 64, wc = (w & 1) * 64;
  f32x4 acc[4][4] = {};

  auto compute = [&](int cur) {
    bf16x8 a[4];
#pragma unroll
    for (int m = 0; m < 4; ++m)
      a[m] = *(const bf16x8*)&sA[cur][(wr + m * 16 + r) * 32 + g * 8];
#pragma unroll
    for (int n = 0; n < 4; ++n) {
      bf16x8 bv = *(const bf16x8*)&sB[cur][(wc + n * 16 + r) * 32 + g * 8];
#pragma unroll
      for (int m = 0; m < 4; ++m)
        acc[m][n] = __builtin_amdgcn_mfma_f32_16x16x32_bf16(a[m], bv, acc[m][n], 0, 0, 0);
    }
  };

  stage128x32(A, E_DIM, sA[0], w, ln);
  stage128x32(B, E_DIM, sB[0], w, ln);
  __syncthreads();
  int cur = 0;
  for (int k0 = 32; k0 < E_DIM; k0 += 32) {
    stage128x32(A + k0, E_DIM, sA[cur ^ 1], w, ln);
    stage128x32(B + k0, E_DIM, sB[cur ^ 1], w, ln);
    compute(cur);
    __syncthreads();
    cur ^= 1;
  }
  compute(cur);

#pragma unroll
  for (int n = 0; n < 4; ++n) {
    const int col = n0 + wc + n * 16 + r;
    const float bv = bias[col];
#pragma unroll
    for (int m = 0; m < 4; ++m)
#pragma unroll
      for (int j = 0; j < 4; ++j) {
        const int row = m0 + wr + m * 16 + g * 4 + j;
        C[(size_t)row * QKV_N + col] = __float2bfloat16(acc[m][n][j] + bv);
      }
  }
}

// ---- V transpose (vectorized): Qkv v-section -> Vt[h][d(96)][s] ----------
// grid (19, 64): bx<18 transpose 64hd x 64s tiles; bx==18 zero-fills
// Vt rows d=72..79 (the PV pad). 256 threads.
__global__ void k_vtrans(const bf16* __restrict__ Qkv, bf16* __restrict__ Vt) {
  __shared__ bf16 tl[64][76];    // pad 72->76 elems to spread banks
  const int t = threadIdx.x, bx = blockIdx.x, by = blockIdx.y;
  if (bx == 18) {                // zero-fill Vt[h][72..79][by*64 ..]
    const u32x4 z = {0, 0, 0, 0};
#pragma unroll
    for (int it = 0; it < 4; ++it) {
      const int zi = t * 4 + it;          // 0..1023 (16B units)
      const int u = zi & 7, hd = zi >> 3; // hd = h*8 + (d-72)
      const int h = hd >> 3, dp = hd & 7;
      *(u32x4*)(Vt + ((size_t)h * HDP + 72 + dp) * S_TOT + by * 64 + u * 8) = z;
    }
    return;
  }
  const int hd0 = bx * 64, s0 = by * 64;
  const int row = t >> 2, cq = t & 3;
  const bf16* src = Qkv + (size_t)(s0 + row) * QKV_N + 2304 + hd0;
  const u32x4 va = *(const u32x4*)(src + cq * 8);
  const u32x4 vb = *(const u32x4*)(src + 32 + cq * 8);
  const unsigned short* pa = (const unsigned short*)&va;
  const unsigned short* pb = (const unsigned short*)&vb;
#pragma unroll
  for (int i = 0; i < 8; ++i) {
    *(unsigned short*)&tl[cq * 8 + i][row]      = pa[i];
    *(unsigned short*)&tl[32 + cq * 8 + i][row] = pb[i];
  }
  __syncthreads();
  const int col = t >> 2, rq = t & 3;
  const int hd = hd0 + col;
  const int h = hd / HD, dd = hd % HD;
  bf16* dst = Vt + ((size_t)h * HDP + dd) * S_TOT + s0;
  *(u32x4*)(dst + rq * 8)      = *(const u32x4*)&tl[col][rq * 8];
  *(u32x4*)(dst + 32 + rq * 8) = *(const u32x4*)&tl[col][32 + rq * 8];
}

// ------- RoPE (vectorized quads) -> bf16 q,k head-major [h][s][96] --------
// 12 quad-slots per (s,h): qi<9 compute d=4*qi (writes quads qi and qi+9);
// qi>=9 writes two zero quads of the d=72..95 pad. q pre-scaled by SCALE_QK.
__global__ void k_rope(const bf16* __restrict__ Qkv,
                       const float* __restrict__ cs, const float* __restrict__ sn,
                       bf16* __restrict__ Qh, bf16* __restrict__ Kh) {
  const int i = blockIdx.x * 256 + threadIdx.x;   // [0, 4096*16*12)
  const int qi = i % 12;
  const int h = (i / 12) & 15;
  const int s = i / 192;
  bf16* qo = Qh + ((size_t)h * S_TOT + s) * HDP;
  bf16* ko = Kh + ((size_t)h * S_TOT + s) * HDP;
  if (qi >= 9) {
    const int zq = 18 + (qi - 9) * 2;    // elem offset zq*4 in [72,96)
    const u32x4 z = {0, 0, 0, 0};
    *(u32x4*)(qo + zq * 4) = z;
    *(u32x4*)(ko + zq * 4) = z;
    return;
  }
  const int d = qi * 4;
  const float4 c0 = *(const float4*)(cs + s * HD + d);
  const float4 c1 = *(const float4*)(cs + s * HD + d + 36);
  const float4 s0 = *(const float4*)(sn + s * HD + d);
  const float4 s1 = *(const float4*)(sn + s * HD + d + 36);
  const bf16* qsrc = Qkv + (size_t)s * QKV_N + h * HD + d;
  {
    const u32x2 u0 = *(const u32x2*)qsrc;
    const u32x2 u1 = *(const u32x2*)(qsrc + 36);
    const float x0[4] = {bl16(u0.x), bh16(u0.x), bl16(u0.y), bh16(u0.y)};
    const float x1[4] = {bl16(u1.x), bh16(u1.x), bl16(u1.y), bh16(u1.y)};
    u32x2 o0, o1;
    o0.x = pack2((x0[0]*c0.x - x1[0]*s0.x)*SCALE_QK, (x0[1]*c0.y - x1[1]*s0.y)*SCALE_QK);
    o0.y = pack2((x0[2]*c0.z - x1[2]*s0.z)*SCALE_QK, (x0[3]*c0.w - x1[3]*s0.w)*SCALE_QK);
    o1.x = pack2((x1[0]*c1.x + x0[0]*s1.x)*SCALE_QK, (x1[1]*c1.y + x0[1]*s1.y)*SCALE_QK);
    o1.y = pack2((x1[2]*c1.z + x0[2]*s1.z)*SCALE_QK, (x1[3]*c1.w + x0[3]*s1.w)*SCALE_QK);
    *(u32x2*)(qo + d)      = o0;
    *(u32x2*)(qo + d + 36) = o1;
  }
  {
    const bf16* ksrc = qsrc + E_DIM;
    const u32x2 u0 = *(const u32x2*)ksrc;
    const u32x2 u1 = *(const u32x2*)(ksrc + 36);
    const float x0[4] = {bl16(u0.x), bh16(u0.x), bl16(u0.y), bh16(u0.y)};
    const float x1[4] = {bl16(u1.x), bh16(u1.x), bl16(u1.y), bh16(u1.y)};
    u32x2 o0, o1;
    o0.x = pack2(x0[0]*c0.x - x1[0]*s0.x, x0[1]*c0.y - x1[1]*s0.y);
    o0.y = pack2(x0[2]*c0.z - x1[2]*s0.z, x0[3]*c0.w - x1[3]*s0.w);
    o1.x = pack2(x1[0]*c1.x + x0[0]*s1.x, x1[1]*c1.y + x0[1]*s1.y);
    o1.y = pack2(x1[2]*c1.z + x0[2]*s1.z, x1[3]*c1.w + x0[3]*s1.w);
    *(u32x2*)(ko + d)      = o0;
    *(u32x2*)(ko + d + 36) = o1;
  }
}

// ---------------- flash attention (unchanged from R6/R7) ----------------
__global__ __launch_bounds__(256, 2)
void k_flash(const bf16* __restrict__ Qh, const bf16* __restrict__ Kh,
             const bf16* __restrict__ Vt, bf16* __restrict__ Jb) {
  __shared__ bf16 sK[128 * 96];
  __shared__ bf16 sV[96 * 128];
  __shared__ bf16 sP[4 * 4096];
  const int w = threadIdx.x >> 6, ln = threadIdx.x & 63;
  const int r = ln & 15, g = ln >> 4;
  const int hc = blockIdx.x;
  const int h = hc >> 2, s0 = (hc & 3) * CLEN;
  const int q0 = blockIdx.y * 128;
  const bf16* Qg = Qh + ((size_t)h * S_TOT + s0 + q0) * HDP;
  const bf16* Kg = Kh + ((size_t)h * S_TOT + s0) * HDP;
  const bf16* Vg = Vt + (size_t)h * HDP * S_TOT + s0;

  stage128x96(Qg, sP, w, ln);
  __syncthreads();
  const char* sPb = (const char*)sP;
  bf16x8 qa[2][3];
#pragma unroll
  for (int m = 0; m < 2; ++m)
#pragma unroll
    for (int ks = 0; ks < 3; ++ks) {
      const int row = w * 32 + m * 16 + r;
      qa[m][ks] = *(const bf16x8*)(sPb + row * 192 + (((ks * 4 + g) ^ (row & 3)) << 4));
    }

  f32x4 oacc[2][5] = {};
  float mrun[2] = {-1e30f, -1e30f}, lrun[2] = {0.f, 0.f};

  char* sPw = (char*)sP + w * 8192;
  const char* sKb = (const char*)sK;
  const char* sVb = (const char*)sV;
  const int ksw = r & 3;

  for (int t = 0; t < 8; ++t) {
    __syncthreads();
    stage128x96(Kg + t * 128 * HDP, sK, w, ln);
    stageVt5(Vg + t * 128, sV, w, ln);
    asm volatile("s_waitcnt vmcnt(5)" ::: "memory");
    __builtin_amdgcn_s_barrier();

    f32x4 acc[2][8] = {};
#pragma unroll
    for (int kvb = 0; kvb < 8; ++kvb) {
      bf16x8 ka[3];
      const int row = kvb * 16 + r;
#pragma unroll
      for (int ks = 0; ks < 3; ++ks)
        ka[ks] = *(const bf16x8*)(sKb + row * 192 + (((ks * 4 + g) ^ ksw) << 4));
#pragma unroll
      for (int ks = 0; ks < 3; ++ks) {
        acc[0][kvb] = __builtin_amdgcn_mfma_f32_16x16x32_bf16(ka[ks], qa[0][ks], acc[0][kvb], 0, 0, 0);
        acc[1][kvb] = __builtin_amdgcn_mfma_f32_16x16x32_bf16(ka[ks], qa[1][ks], acc[1][kvb], 0, 0, 0);
      }
    }

    float escr[2];
#pragma unroll
    for (int m = 0; m < 2; ++m) {
      float tm = acc[m][0][0];
#pragma unroll
      for (int kvb = 0; kvb < 8; ++kvb)
#pragma unroll
        for (int j = 0; j < 4; ++j) tm = fmaxf(tm, acc[m][kvb][j]);
      tm = fmaxf(tm, __shfl_xor(tm, 16));
      tm = fmaxf(tm, __shfl_xor(tm, 32));
      const float mn = fmaxf(mrun[m], tm);
      escr[m] = __expf(mrun[m] - mn);
      mrun[m] = mn;
      float sm = 0.f;
#pragma unroll
      for (int kvb = 0; kvb < 8; ++kvb)
#pragma unroll
        for (int j = 0; j < 4; ++j) {
          const float p = __expf(acc[m][kvb][j] - mn);
          acc[m][kvb][j] = p; sm += p;
        }
      sm += __shfl_xor(sm, 16);
      sm += __shfl_xor(sm, 32);
      lrun[m] = lrun[m] * escr[m] + sm;
    }
#pragma unroll
    for (int m = 0; m < 2; ++m)
#pragma unroll
      for (int j = 0; j < 4; ++j) {
        const float e = __shfl(escr[m], (ln & 48) | (g * 4 + j));
#pragma unroll
        for (int n = 0; n < 5; ++n) oacc[m][n][j] *= e;
      }

#pragma unroll
    for (int m = 0; m < 2; ++m)
#pragma unroll
      for (int kvb = 0; kvb < 8; ++kvb) {
        u32x2 u;
        u.x = pack2(acc[m][kvb][0], acc[m][kvb][1]);
        u.y = pack2(acc[m][kvb][2], acc[m][kvb][3]);
        const int gsw = (kvb * 2 + (g >> 1)) ^ (r & 7);
        *(u32x2*)(sPw + m * 4096 + r * 256 + (gsw << 4) + (g & 1) * 8) = u;
      }

    asm volatile("s_waitcnt vmcnt(0)" ::: "memory");
    __builtin_amdgcn_s_barrier();

#pragma unroll
    for (int ks = 0; ks < 4; ++ks) {
      bf16x8 pa[2];
#pragma unroll
      for (int m = 0; m < 2; ++m)
        pa[m] = *(const bf16x8*)(sPw + m * 4096 + r * 256 +
                                 (((ks * 4 + g) ^ (r & 7)) << 4));
#pragma unroll
      for (int n = 0; n < 5; ++n) {
        const int d = n * 16 + r;
        bf16x8 vb = *(const bf16x8*)(sVb + d * 256 + (((ks * 4 + g) ^ (d & 7)) << 4));
        oacc[0][n] = __builtin_amdgcn_mfma_f32_16x16x32_bf16(pa[0], vb, oacc[0][n], 0, 0, 0);
        oacc[1][n] = __builtin_amdgcn_mfma_f32_16x16x32_bf16(pa[1], vb, oacc[1][n], 0, 0, 0);
      }
    }
  }

#pragma unroll
  for (int m = 0; m < 2; ++m) {
    float inv[4];
#pragma unroll
    for (int j = 0; j < 4; ++j)
      inv[j] = 1.0f / __shfl(lrun[m], (ln & 48) | (g * 4 + j));
#pragma unroll
    for (int n = 0; n < 5; ++n) {
      const int d = n * 16 + r;
      if (d < HD) {
#pragma unroll
        for (int j = 0; j < 4; ++j) {
          const int row = s0 + q0 + w * 32 + m * 16 + g * 4 + j;
          Jb[(size_t)row * E_DIM + h * HD + d] = __float2bfloat16(oacc[m][n][j] * inv[j]);
        }
      }
    }
  }
}

// ------- out = attn @ proj_w^T + proj_b, 2-phase double-buffered ----------
__global__ __launch_bounds__(256, 2)
void k_proj(const bf16* __restrict__ Jb, const bf16* __restrict__ Pw,
            const float* __restrict__ bias, float* __restrict__ out) {
  __shared__ bf16 sA[2][128 * 32], sB[2][128 * 32];
  const int w = threadIdx.x >> 6, ln = threadIdx.x & 63;
  const int m0 = blockIdx.x * 128, n0 = blockIdx.y * 128;
  const bf16* A = Jb + (size_t)m0 * E_DIM;
  const bf16* B = Pw + (size_t)n0 * E_DIM;
  const int r = ln & 15, g = ln >> 4;
  const int wr = (w >> 1) * 64, wc = (w & 1) * 64;
  f32x4 acc[4][4] = {};

  auto compute = [&](int cur) {
    bf16x8 a[4];
#pragma unroll
    for (int m = 0; m < 4; ++m)
      a[m] = *(const bf16x8*)&sA[cur][(wr + m * 16 + r) * 32 + g * 8];
#pragma unroll
    for (int n = 0; n < 4; ++n) {
      bf16x8 bv = *(const bf16x8*)&sB[cur][(wc + n * 16 + r) * 32 + g * 8];
#pragma unroll
      for (int m = 0; m < 4; ++m)
        acc[m][n] = __builtin_amdgcn_mfma_f32_16x16x32_bf16(a[m], bv, acc[m][n], 0, 0, 0);
    }
  };

  stage128x32(A, E_DIM, sA[0], w, ln);
  stage128x32(B, E_DIM, sB[0], w, ln);
  __syncthreads();
  int cur = 0;
  for (int k0 = 32; k0 < E_DIM; k0 += 32) {
    stage128x32(A + k0, E_DIM, sA[cur ^ 1], w, ln);
    stage128x32(B + k0, E_DIM, sB[cur ^ 1], w, ln);
    compute(cur);
    __syncthreads();
    cur ^= 1;
  }
  compute(cur);

#pragma unroll
  for (int n = 0; n < 4; ++n) {
    const int col = n0 + wc + n * 16 + r;
    const float bv = bias[col];
#pragma unroll
    for (int m = 0; m < 4; ++m)
#pragma unroll
      for (int j = 0; j < 4; ++j) {
        const int row = m0 + wr + m * 16 + g * 4 + j;
        out[(size_t)row * E_DIM + col] = acc[m][n][j] + bv;
      }
  }
}

// --------------------------------- launch ---------------------------------
extern "C" void kernel_launch(void* const* d_in, const int* in_sizes, int n_in,
                              void* d_out, int out_size, void* d_ws, size_t ws_size,
                              hipStream_t stream) {
  (void)in_sizes; (void)n_in; (void)out_size; (void)ws_size;
  const float* hs   = (const float*)d_in[0];
  const float* cosp = (const float*)d_in[1];
  const float* sinp = (const float*)d_in[2];
  const float* qkvw = (const float*)d_in[3];
  const float* qkvb = (const float*)d_in[4];
  const float* pw   = (const float*)d_in[5];
  const float* pb   = (const float*)d_in[6];
  float* out = (float*)d_out;
  char* ws = (char*)d_ws;

  bf16* Ab   = (bf16*)(ws + 0);          // hs bf16 [4096][1152]
  bf16* Wb   = (bf16*)(ws + 9437184);    // qkv_w bf16 [3456][1152]
  bf16* Pw   = (bf16*)(ws + 17399808);   // proj_w bf16 [1152][1152]
  bf16* Qkv  = (bf16*)(ws + 20054016);   // qkv out bf16 [4096][3456]
  bf16* Qh   = (bf16*)(ws + 48365568);   // q bf16 [16][4096][96], scaled
  bf16* Kh   = (bf16*)(ws + 60948480);   // k bf16 [16][4096][96]
  bf16* Vt   = (bf16*)(ws + 73531392);   // v^T bf16 [16][96][4096]
  bf16* Jb   = (bf16*)(ws + 86114304);   // attn bf16 [4096][1152]
  // total 95551488 bytes (~91 MiB)

  k_pack_all<<<9792, 256, 0, stream>>>(hs, qkvw, pw, Ab);
  k_qkv_gemm<<<dim3(32, 27), 256, 0, stream>>>(Ab, Wb, qkvb, Qkv);
  k_vtrans<<<dim3(19, 64), 256, 0, stream>>>(Qkv, Vt);
  k_rope<<<3072, 256, 0, stream>>>(Qkv, cosp, sinp, Qh, Kh);
  k_flash<<<dim3(64, 8), 256, 0, stream>>>(Qh, Kh, Vt, Jb);
  k_proj<<<dim3(32, 9), 256, 0, stream>>>(Jb, Pw, pb, out);
}